// Round 8
// baseline (348.345 us; speedup 1.0000x reference)
//
#include <hip/hip_runtime.h>

#define DIN 256
#define DH  256
#define DOUT 128
#define H1OFF 16384   // byte offset of h1 tile inside mega-kernel LDS

typedef __attribute__((ext_vector_type(8))) short bf16x8;
typedef __attribute__((ext_vector_type(4))) float f32x4;
typedef __attribute__((ext_vector_type(8))) unsigned short ushort8v;

static __device__ __forceinline__ unsigned short f2bf(float x) {
    unsigned u = __float_as_uint(x);
    u += 0x7fffu + ((u >> 16) & 1u);          // round-to-nearest-even
    return (unsigned short)(u >> 16);
}
static __device__ __forceinline__ float bf2f(unsigned short h) {
    return __uint_as_float(((unsigned)h) << 16);
}

static __device__ __forceinline__ void gload16(const unsigned short* g, void* l) {
    __builtin_amdgcn_global_load_lds(
        (const __attribute__((address_space(1))) unsigned int*)g,
        (__attribute__((address_space(3))) unsigned int*)l,
        16, 0, 0);
}

// ======== prep: feat->bf16 | weight transposes (ws1t, wn1t, wcat) | degree count ========
__global__ void prep_kernel(const float* __restrict__ feat, unsigned short* __restrict__ featb, long long n8,
                            const float* __restrict__ w_self1, const float* __restrict__ w_neigh1,
                            const float* __restrict__ w_self2, const float* __restrict__ w_neigh2,
                            unsigned short* __restrict__ ws1t, unsigned short* __restrict__ wn1t,
                            unsigned short* __restrict__ wcat,
                            const int* __restrict__ dst, int* __restrict__ cnt, int E,
                            int bCvt, int bWt) {
    int b = blockIdx.x;
    if (b < bCvt) {
        long long i = b * 256LL + threadIdx.x;
        if (i >= n8) return;
        const f32x4* p = (const f32x4*)(feat + i * 8);
        f32x4 a = __builtin_nontemporal_load(p);
        f32x4 c = __builtin_nontemporal_load(p + 1);
        ushort8v o;
        o[0] = f2bf(a[0]); o[1] = f2bf(a[1]); o[2] = f2bf(a[2]); o[3] = f2bf(a[3]);
        o[4] = f2bf(c[0]); o[5] = f2bf(c[1]); o[6] = f2bf(c[2]); o[7] = f2bf(c[3]);
        *(ushort8v*)(featb + i * 8) = o;
    } else if (b < bCvt + bWt) {
        int idx = (b - bCvt) * 256 + threadIdx.x;
        if (idx < 65536) {                      // ws1t[n][k] = w_self1[k][n]
            int nn = idx >> 8, k = idx & 255;
            ws1t[idx] = f2bf(w_self1[k * 256 + nn]);
        } else if (idx < 131072) {              // wn1t
            int j = idx - 65536; int nn = j >> 8, k = j & 255;
            wn1t[j] = f2bf(w_neigh1[k * 256 + nn]);
        } else if (idx < 163840) {              // wcat rows 0..127 = wn2^T
            int j = idx - 131072; int nn = j >> 8, k = j & 255;
            wcat[j] = f2bf(w_neigh2[k * 128 + nn]);
        } else if (idx < 196608) {              // wcat rows 128..255 = ws2^T
            int j = idx - 163840; int nn = j >> 8, k = j & 255;
            wcat[32768 + j] = f2bf(w_self2[k * 128 + nn]);
        }
    } else {
        int e = (b - bCvt - bWt) * 256 + threadIdx.x;
        if (e < E) atomicAdd(&cnt[dst[e]], 1);
    }
}

// ================= CSR scan / fill =================
__global__ void block_sums_kernel(const int* __restrict__ cnt, int* __restrict__ partial, int N) {
    __shared__ int sdata[256];
    int t = threadIdx.x;
    int base = blockIdx.x * 1024;
    int s = 0;
#pragma unroll
    for (int j = 0; j < 4; ++j) {
        int i = base + t * 4 + j;
        if (i < N) s += cnt[i];
    }
    sdata[t] = s; __syncthreads();
    for (int o = 128; o; o >>= 1) {
        if (t < o) sdata[t] += sdata[t + o];
        __syncthreads();
    }
    if (t == 0) partial[blockIdx.x] = sdata[0];
}

__global__ void scan_partials_kernel(int* __restrict__ partial, int nb) {
    __shared__ int sdata[256];
    int t = threadIdx.x;
    int v = (t < nb) ? partial[t] : 0;
    sdata[t] = v; __syncthreads();
    for (int o = 1; o < 256; o <<= 1) {
        int y = (t >= o) ? sdata[t - o] : 0;
        __syncthreads();
        sdata[t] += y;
        __syncthreads();
    }
    if (t < nb) partial[t] = sdata[t] - v;
}

// writes offsets AND initializes the fill-cursor (same values)
__global__ void scan_block_kernel(int* __restrict__ cnt, const int* __restrict__ partial,
                                  int* __restrict__ off, int N, int E) {
    __shared__ int sdata[256];
    int b = blockIdx.x, t = threadIdx.x;
    int base = b * 1024;
    int vals[4]; int local = 0;
#pragma unroll
    for (int j = 0; j < 4; ++j) {
        int i = base + t * 4 + j;
        vals[j] = (i < N) ? cnt[i] : 0;
        local += vals[j];
    }
    sdata[t] = local; __syncthreads();
    for (int o = 1; o < 256; o <<= 1) {
        int y = (t >= o) ? sdata[t - o] : 0;
        __syncthreads();
        sdata[t] += y;
        __syncthreads();
    }
    int run = sdata[t] - local + partial[b];
#pragma unroll
    for (int j = 0; j < 4; ++j) {
        int i = base + t * 4 + j;
        if (i < N) { off[i] = run; cnt[i] = run; }   // cnt becomes cursor
        run += vals[j];
    }
    if (b == 0 && t == 0) off[N] = E;
}

__global__ void fill_csr_kernel(const int* __restrict__ src, const int* __restrict__ dst,
                                int* __restrict__ cursor, int* __restrict__ csr, int E) {
    int e = blockIdx.x * blockDim.x + threadIdx.x;
    if (e < E) {
        int d = dst[e];
        int p = atomicAdd(&cursor[d], 1);
        csr[p] = src[e];
    }
}

// ================= gather-mean D=256: 2 rows per load (half-wave each, 16B/lane) ======
__global__ void gather_mean256_kernel(const unsigned short* __restrict__ p, const int* __restrict__ off,
                                      const int* __restrict__ csr, unsigned short* __restrict__ agg, int N) {
    int wid  = (int)((blockIdx.x * (long long)blockDim.x + threadIdx.x) >> 6);
    int lane = threadIdx.x & 63;
    if (wid >= N) return;
    int start = off[wid], end = off[wid + 1];
    const int half = lane >> 5;          // 0/1: which row of the pair
    const int c8   = (lane & 31) * 8;    // 8 cols per lane -> 256
    float a[8] = {};
    int e = start;
    for (; e + 3 < end; e += 4) {        // 2 pairs in flight
        int s0 = csr[e + half], s1 = csr[e + 2 + half];
        ushort8v v0 = *(const ushort8v*)(p + (long long)s0 * 256 + c8);
        ushort8v v1 = *(const ushort8v*)(p + (long long)s1 * 256 + c8);
#pragma unroll
        for (int j = 0; j < 8; ++j) a[j] += bf2f(v0[j]) + bf2f(v1[j]);
    }
    for (; e < end; e += 2) {
        int idx = e + half;
        if (idx < end) {
            int s = csr[idx];
            ushort8v v = *(const ushort8v*)(p + (long long)s * 256 + c8);
#pragma unroll
            for (int j = 0; j < 8; ++j) a[j] += bf2f(v[j]);
        }
    }
#pragma unroll
    for (int j = 0; j < 8; ++j) a[j] += __shfl_xor(a[j], 32);
    if (half == 0) {
        float inv = 1.0f / (float)max(end - start, 1);
        ushort8v o;
#pragma unroll
        for (int j = 0; j < 8; ++j) o[j] = f2bf(a[j] * inv);
        __builtin_nontemporal_store(o, (ushort8v*)(agg + (long long)wid * 256 + c8));
    }
}

// ============ MEGA kernel ============
// phase 1: h1 = relu(feat@Ws1 + agg@Wn1 + b1)  -> LDS (swizzled [128][256] bf16)
// phase 2: [p2 | self2+b2] = h1 @ wcat^T       -> global bf16
// A: LDS double-buffered staging (gload16). B: direct global->reg frags (L2-hot weights).
__global__ __launch_bounds__(512, 4)
void mega_kernel(const unsigned short* __restrict__ featb, const unsigned short* __restrict__ ws1t,
                 const unsigned short* __restrict__ aggb,  const unsigned short* __restrict__ wn1t,
                 const float* __restrict__ b1, const unsigned short* __restrict__ wcat,
                 const float* __restrict__ b2,
                 unsigned short* __restrict__ p2, unsigned short* __restrict__ self2, int M)
{
    __shared__ __align__(16) char lds[16384 + 65536];   // A-stage 2x8KB + h1 64KB

    const int tid = threadIdx.x;
    const int wid = tid >> 6, lane = tid & 63;
    const int l15 = lane & 15, lg = lane >> 4;
    const int wr = wid >> 2, wc = wid & 3;     // 2 x 4 waves over 128 x 256
    const int row0 = blockIdx.x * 128;

    // ---- phase-1 A staging geometry: c = tid over 8KB tile [128 rows][32 k] ----
    long long asrc; int adst;
    {
        int c = tid, r = c >> 2, s = c & 3;
        int kc = s ^ ((r >> 1) & 3);                       // source-side swizzle
        asrc = (long long)min(row0 + r, M - 1) * 256 + kc * 8;
        adst = c * 16;
    }
    // A-frag LDS read offsets (un-swizzle on read)
    const int slot = (lg ^ ((l15 >> 1) & 3)) * 16;
    int aoff[4];
#pragma unroll
    for (int m = 0; m < 4; ++m) aoff[m] = (wr * 64 + m * 16 + l15) * 64 + slot;
    // B global col bases (K=256), shared by phase 1 and phase 2
    long long bcol[4];
#pragma unroll
    for (int n = 0; n < 4; ++n) bcol[n] = (long long)(wc * 64 + n * 16 + l15) * 256;

    f32x4 acc[4][4] = {};

    auto stageA = [&](int buf, int t) {
        const unsigned short* Ap = (t >= 8) ? aggb : featb;
        int k0 = (t & 7) * 32;
        gload16(Ap + asrc + k0, &lds[buf * 8192 + adst]);
    };

    stageA(0, 0);
    __syncthreads();

    for (int t = 0; t < 16; ++t) {
        const int cur = t & 1;
        if (t + 1 < 16) stageA(cur ^ 1, t + 1);
        const unsigned short* Bp = (t >= 8) ? wn1t : ws1t;
        const int k0 = (t & 7) * 32 + lg * 8;
        bf16x8 af[4], bfr[4];
#pragma unroll
        for (int n = 0; n < 4; ++n) bfr[n] = *(const bf16x8*)(Bp + bcol[n] + k0);
#pragma unroll
        for (int m = 0; m < 4; ++m) af[m] = *(const bf16x8*)(lds + cur * 8192 + aoff[m]);
#pragma unroll
        for (int m = 0; m < 4; ++m)
#pragma unroll
            for (int n = 0; n < 4; ++n)
                acc[m][n] = __builtin_amdgcn_mfma_f32_16x16x32_bf16(af[m], bfr[n], acc[m][n], 0, 0, 0);
        __syncthreads();
    }

    // ---- phase 1.5: h1 -> LDS, relu+bias, bf16, XOR-swizzled [row][k] rowstride 512B ----
    {
        float bv[4];
#pragma unroll
        for (int n = 0; n < 4; ++n) bv[n] = b1[wc * 64 + n * 16 + l15];
#pragma unroll
        for (int m = 0; m < 4; ++m)
#pragma unroll
            for (int rr = 0; rr < 4; ++rr) {
                int rowl = wr * 64 + m * 16 + lg * 4 + rr;
#pragma unroll
                for (int n = 0; n < 4; ++n) {
                    int col = wc * 64 + n * 16 + l15;
                    float v = fmaxf(acc[m][n][rr] + bv[n], 0.f);
                    int sl = (col >> 3) ^ (rowl & 7);
                    *(unsigned short*)(lds + H1OFF + rowl * 512 + (sl << 4) + ((col & 7) << 1)) = f2bf(v);
                }
            }
    }
    __syncthreads();

    // ---- phase 2: 128 x 256 = h1(LDS) @ wcat (cols 0-127 -> p2, 128-255 -> self2) ----
    f32x4 a2[4][4] = {};
    int arow2[4];
#pragma unroll
    for (int m = 0; m < 4; ++m) arow2[m] = wr * 64 + m * 16 + l15;

#pragma unroll
    for (int t = 0; t < 8; ++t) {
        bf16x8 af[4], bfr[4];
#pragma unroll
        for (int m = 0; m < 4; ++m) {
            int row = arow2[m];
            int sl = (t * 4 + lg) ^ (row & 7);
            af[m] = *(const bf16x8*)(lds + H1OFF + row * 512 + (sl << 4));
        }
        const int k0 = t * 32 + lg * 8;
#pragma unroll
        for (int n = 0; n < 4; ++n) bfr[n] = *(const bf16x8*)(wcat + bcol[n] + k0);
#pragma unroll
        for (int m = 0; m < 4; ++m)
#pragma unroll
            for (int n = 0; n < 4; ++n)
                a2[m][n] = __builtin_amdgcn_mfma_f32_16x16x32_bf16(af[m], bfr[n], a2[m][n], 0, 0, 0);
    }

    // ---- epilogue: wc 0/1 -> p2 (plain); wc 2/3 -> self2 (+b2, no relu) ----
    if (wc < 2) {
#pragma unroll
        for (int m = 0; m < 4; ++m)
#pragma unroll
            for (int rr = 0; rr < 4; ++rr) {
                int grow = row0 + wr * 64 + m * 16 + lg * 4 + rr;
                if (grow >= M) continue;
#pragma unroll
                for (int n = 0; n < 4; ++n) {
                    int col = wc * 64 + n * 16 + l15;
                    __builtin_nontemporal_store(f2bf(a2[m][n][rr]),
                        &p2[(long long)grow * 128 + col]);
                }
            }
    } else {
        float bv[4];
#pragma unroll
        for (int n = 0; n < 4; ++n) bv[n] = b2[(wc - 2) * 64 + n * 16 + l15];
#pragma unroll
        for (int m = 0; m < 4; ++m)
#pragma unroll
            for (int rr = 0; rr < 4; ++rr) {
                int grow = row0 + wr * 64 + m * 16 + lg * 4 + rr;
                if (grow >= M) continue;
#pragma unroll
                for (int n = 0; n < 4; ++n) {
                    int col = (wc - 2) * 64 + n * 16 + l15;
                    __builtin_nontemporal_store(f2bf(a2[m][n][rr] + bv[n]),
                        &self2[(long long)grow * 128 + col]);
                }
            }
    }
}

// ===== gather128 + final: out = normalize(relu(self2 + mean_nb(p2))) , one wave/node =====
__global__ void gather_final_kernel(const unsigned short* __restrict__ p2, const int* __restrict__ off,
                                    const int* __restrict__ csr, const unsigned short* __restrict__ self2,
                                    float* __restrict__ out, int N) {
    int wid  = (int)((blockIdx.x * (long long)blockDim.x + threadIdx.x) >> 6);
    int lane = threadIdx.x & 63;
    if (wid >= N) return;
    int start = off[wid], end = off[wid + 1];
    const int g  = lane >> 4;            // 0..3: which row of the quad
    const int c8 = (lane & 15) * 8;      // 8 cols per lane -> 128
    float a[8] = {};
    int e = start;
    for (; e + 7 < end; e += 8) {        // 2 quads in flight
        int s0 = csr[e + g], s1 = csr[e + 4 + g];
        ushort8v v0 = *(const ushort8v*)(p2 + (long long)s0 * 128 + c8);
        ushort8v v1 = *(const ushort8v*)(p2 + (long long)s1 * 128 + c8);
#pragma unroll
        for (int j = 0; j < 8; ++j) a[j] += bf2f(v0[j]) + bf2f(v1[j]);
    }
    for (; e < end; e += 4) {
        int idx = e + g;
        if (idx < end) {
            int s = csr[idx];
            ushort8v v = *(const ushort8v*)(p2 + (long long)s * 128 + c8);
#pragma unroll
            for (int j = 0; j < 8; ++j) a[j] += bf2f(v[j]);
        }
    }
#pragma unroll
    for (int j = 0; j < 8; ++j) {
        a[j] += __shfl_xor(a[j], 16);
        a[j] += __shfl_xor(a[j], 32);
    }
    float invd = 1.0f / (float)max(end - start, 1);
    ushort8v sv = *(const ushort8v*)(self2 + (long long)wid * 128 + c8);
    float v[8];
    float ss = 0.f;
#pragma unroll
    for (int j = 0; j < 8; ++j) {
        v[j] = fmaxf(bf2f(sv[j]) + a[j] * invd, 0.f);
        ss += v[j] * v[j];
    }
    ss += __shfl_xor(ss, 1);
    ss += __shfl_xor(ss, 2);
    ss += __shfl_xor(ss, 4);
    ss += __shfl_xor(ss, 8);
    float inv = 1.0f / fmaxf(sqrtf(ss), 1e-12f);
    if (g == 0) {
        f32x4 o0 = { v[0] * inv, v[1] * inv, v[2] * inv, v[3] * inv };
        f32x4 o1 = { v[4] * inv, v[5] * inv, v[6] * inv, v[7] * inv };
        float* dstp = out + (long long)wid * 128 + c8;
        __builtin_nontemporal_store(o0, (f32x4*)dstp);
        __builtin_nontemporal_store(o1, (f32x4*)(dstp + 4));
    }
}

extern "C" void kernel_launch(void* const* d_in, const int* in_sizes, int n_in,
                              void* d_out, int out_size, void* d_ws, size_t ws_size,
                              hipStream_t stream) {
    const float* feat     = (const float*)d_in[0];
    const int*   src      = (const int*)  d_in[1];
    const int*   dst      = (const int*)  d_in[2];
    const float* w_self1  = (const float*)d_in[3];
    const float* w_neigh1 = (const float*)d_in[4];
    const float* b1       = (const float*)d_in[5];
    const float* w_self2  = (const float*)d_in[6];
    const float* w_neigh2 = (const float*)d_in[7];
    const float* b2       = (const float*)d_in[8];
    float* out = (float*)d_out;

    const int N = in_sizes[0] / DIN;    // 100000
    const int E = in_sizes[1];          // 800000

    char* ws = (char*)d_ws;
    auto a4k = [](size_t x) { return (x + 4095) & ~(size_t)4095; };
    size_t o = 0;
    int* cnt  = (int*)(ws + o); o += a4k((size_t)N * 4);
    int* off  = (int*)(ws + o); o += a4k((size_t)(N + 1) * 4);
    int* part = (int*)(ws + o); o += a4k(1024);
    int* csr  = (int*)(ws + o); o += a4k((size_t)E * 4);
    unsigned short* ws1t = (unsigned short*)(ws + o); o += a4k((size_t)DIN * DH * 2);
    unsigned short* wn1t = (unsigned short*)(ws + o); o += a4k((size_t)DIN * DH * 2);
    unsigned short* wcat = (unsigned short*)(ws + o); o += a4k((size_t)256 * 256 * 2);
    unsigned short* featb = (unsigned short*)(ws + o); o += a4k((size_t)N * DIN * 2);
    unsigned short* aggb  = (unsigned short*)(ws + o); o += a4k((size_t)N * DIN * 2);
    unsigned short* p2b   = (unsigned short*)(ws + o); o += a4k((size_t)N * DOUT * 2);
    unsigned short* self2b= (unsigned short*)(ws + o); o += a4k((size_t)N * DOUT * 2);

    const int nblk = (N + 1023) / 1024;

    // ---- prep: cvt + wtrans + count (cnt zeroed first) ----
    hipMemsetAsync(cnt, 0, (size_t)N * 4, stream);
    long long n8 = (long long)N * DIN / 8;
    const int bCvt = (int)((n8 + 255) / 256);       // 12500
    const int bWt  = 768;
    const int bCnt = (E + 255) / 256;               // 3125
    prep_kernel<<<bCvt + bWt + bCnt, 256, 0, stream>>>(
        feat, featb, n8, w_self1, w_neigh1, w_self2, w_neigh2,
        ws1t, wn1t, wcat, dst, cnt, E, bCvt, bWt);

    // ---- CSR scan + fill ----
    block_sums_kernel<<<nblk, 256, 0, stream>>>(cnt, part, N);
    scan_partials_kernel<<<1, 256, 0, stream>>>(part, nblk);
    scan_block_kernel<<<nblk, 256, 0, stream>>>(cnt, part, off, N, E);   // also inits cursor (cnt)
    fill_csr_kernel<<<(E + 255) / 256, 256, 0, stream>>>(src, dst, cnt, csr, E);

    const int mblk = (N + 127) / 128;   // 782

    // ---- layer 1 aggregation + fused layer1-GEMM/layer2-projections ----
    gather_mean256_kernel<<<(N + 3) / 4, 256, 0, stream>>>(featb, off, csr, aggb, N);
    mega_kernel<<<mblk, 512, 0, stream>>>(featb, ws1t, aggb, wn1t, b1, wcat, b2, p2b, self2b, N);

    // ---- layer 2 aggregation + fused epilogue + normalize ----
    gather_final_kernel<<<(N + 3) / 4, 256, 0, stream>>>(p2b, off, csr, self2b, out, N);
}

// Round 9
// 312.164 us; speedup vs baseline: 1.1159x; 1.1159x over previous
//
#include <hip/hip_runtime.h>

#define DIN 256
#define DH  256
#define DOUT 128

typedef __attribute__((ext_vector_type(8))) short bf16x8;
typedef __attribute__((ext_vector_type(4))) float f32x4;
typedef __attribute__((ext_vector_type(8))) unsigned short ushort8v;

static __device__ __forceinline__ unsigned short f2bf(float x) {
    unsigned u = __float_as_uint(x);
    u += 0x7fffu + ((u >> 16) & 1u);          // round-to-nearest-even
    return (unsigned short)(u >> 16);
}
static __device__ __forceinline__ float bf2f(unsigned short h) {
    return __uint_as_float(((unsigned)h) << 16);
}

static __device__ __forceinline__ void gload16(const unsigned short* g, void* l) {
    __builtin_amdgcn_global_load_lds(
        (const __attribute__((address_space(1))) unsigned int*)g,
        (__attribute__((address_space(3))) unsigned int*)l,
        16, 0, 0);
}

// ======== prep: feat->bf16 | weight transposes (ws1t, wn1t, wcat) | degree count ========
__global__ void prep_kernel(const float* __restrict__ feat, unsigned short* __restrict__ featb, long long n8,
                            const float* __restrict__ w_self1, const float* __restrict__ w_neigh1,
                            const float* __restrict__ w_self2, const float* __restrict__ w_neigh2,
                            unsigned short* __restrict__ ws1t, unsigned short* __restrict__ wn1t,
                            unsigned short* __restrict__ wcat,
                            const int* __restrict__ dst, int* __restrict__ cnt, int E,
                            int bCvt, int bWt) {
    int b = blockIdx.x;
    if (b < bCvt) {
        long long i = b * 256LL + threadIdx.x;
        if (i >= n8) return;
        const f32x4* p = (const f32x4*)(feat + i * 8);
        f32x4 a = __builtin_nontemporal_load(p);
        f32x4 c = __builtin_nontemporal_load(p + 1);
        ushort8v o;
        o[0] = f2bf(a[0]); o[1] = f2bf(a[1]); o[2] = f2bf(a[2]); o[3] = f2bf(a[3]);
        o[4] = f2bf(c[0]); o[5] = f2bf(c[1]); o[6] = f2bf(c[2]); o[7] = f2bf(c[3]);
        *(ushort8v*)(featb + i * 8) = o;
    } else if (b < bCvt + bWt) {
        int idx = (b - bCvt) * 256 + threadIdx.x;
        if (idx < 65536) {                      // ws1t[n][k] = w_self1[k][n]
            int nn = idx >> 8, k = idx & 255;
            ws1t[idx] = f2bf(w_self1[k * 256 + nn]);
        } else if (idx < 131072) {              // wn1t
            int j = idx - 65536; int nn = j >> 8, k = j & 255;
            wn1t[j] = f2bf(w_neigh1[k * 256 + nn]);
        } else if (idx < 163840) {              // wcat rows 0..127 = wn2^T
            int j = idx - 131072; int nn = j >> 8, k = j & 255;
            wcat[j] = f2bf(w_neigh2[k * 128 + nn]);
        } else if (idx < 196608) {              // wcat rows 128..255 = ws2^T
            int j = idx - 163840; int nn = j >> 8, k = j & 255;
            wcat[32768 + j] = f2bf(w_self2[k * 128 + nn]);
        }
    } else {
        int e = (b - bCvt - bWt) * 256 + threadIdx.x;
        if (e < E) atomicAdd(&cnt[dst[e]], 1);
    }
}

// ================= CSR scan / fill =================
__global__ void block_sums_kernel(const int* __restrict__ cnt, int* __restrict__ partial, int N) {
    __shared__ int sdata[256];
    int t = threadIdx.x;
    int base = blockIdx.x * 1024;
    int s = 0;
#pragma unroll
    for (int j = 0; j < 4; ++j) {
        int i = base + t * 4 + j;
        if (i < N) s += cnt[i];
    }
    sdata[t] = s; __syncthreads();
    for (int o = 128; o; o >>= 1) {
        if (t < o) sdata[t] += sdata[t + o];
        __syncthreads();
    }
    if (t == 0) partial[blockIdx.x] = sdata[0];
}

__global__ void scan_partials_kernel(int* __restrict__ partial, int nb) {
    __shared__ int sdata[256];
    int t = threadIdx.x;
    int v = (t < nb) ? partial[t] : 0;
    sdata[t] = v; __syncthreads();
    for (int o = 1; o < 256; o <<= 1) {
        int y = (t >= o) ? sdata[t - o] : 0;
        __syncthreads();
        sdata[t] += y;
        __syncthreads();
    }
    if (t < nb) partial[t] = sdata[t] - v;
}

// writes offsets AND initializes the fill-cursor (same values)
__global__ void scan_block_kernel(int* __restrict__ cnt, const int* __restrict__ partial,
                                  int* __restrict__ off, int N, int E) {
    __shared__ int sdata[256];
    int b = blockIdx.x, t = threadIdx.x;
    int base = b * 1024;
    int vals[4]; int local = 0;
#pragma unroll
    for (int j = 0; j < 4; ++j) {
        int i = base + t * 4 + j;
        vals[j] = (i < N) ? cnt[i] : 0;
        local += vals[j];
    }
    sdata[t] = local; __syncthreads();
    for (int o = 1; o < 256; o <<= 1) {
        int y = (t >= o) ? sdata[t - o] : 0;
        __syncthreads();
        sdata[t] += y;
        __syncthreads();
    }
    int run = sdata[t] - local + partial[b];
#pragma unroll
    for (int j = 0; j < 4; ++j) {
        int i = base + t * 4 + j;
        if (i < N) { off[i] = run; cnt[i] = run; }   // cnt becomes cursor
        run += vals[j];
    }
    if (b == 0 && t == 0) off[N] = E;
}

__global__ void fill_csr_kernel(const int* __restrict__ src, const int* __restrict__ dst,
                                int* __restrict__ cursor, int* __restrict__ csr, int E) {
    int e = blockIdx.x * blockDim.x + threadIdx.x;
    if (e < E) {
        int d = dst[e];
        int p = atomicAdd(&cursor[d], 1);
        csr[p] = src[e];
    }
}

// ================= gather-mean D=256: 2 rows per load (half-wave each, 16B/lane) ======
__global__ void gather_mean256_kernel(const unsigned short* __restrict__ p, const int* __restrict__ off,
                                      const int* __restrict__ csr, unsigned short* __restrict__ agg, int N) {
    int wid  = (int)((blockIdx.x * (long long)blockDim.x + threadIdx.x) >> 6);
    int lane = threadIdx.x & 63;
    if (wid >= N) return;
    int start = off[wid], end = off[wid + 1];
    const int half = lane >> 5;          // 0/1: which row of the pair
    const int c8   = (lane & 31) * 8;    // 8 cols per lane -> 256
    float a[8] = {};
    int e = start;
    for (; e + 3 < end; e += 4) {        // 2 pairs in flight
        int s0 = csr[e + half], s1 = csr[e + 2 + half];
        ushort8v v0 = *(const ushort8v*)(p + (long long)s0 * 256 + c8);
        ushort8v v1 = *(const ushort8v*)(p + (long long)s1 * 256 + c8);
#pragma unroll
        for (int j = 0; j < 8; ++j) a[j] += bf2f(v0[j]) + bf2f(v1[j]);
    }
    for (; e < end; e += 2) {
        int idx = e + half;
        if (idx < end) {
            int s = csr[idx];
            ushort8v v = *(const ushort8v*)(p + (long long)s * 256 + c8);
#pragma unroll
            for (int j = 0; j < 8; ++j) a[j] += bf2f(v[j]);
        }
    }
#pragma unroll
    for (int j = 0; j < 8; ++j) a[j] += __shfl_xor(a[j], 32);
    if (half == 0) {
        float inv = 1.0f / (float)max(end - start, 1);
        ushort8v o;
#pragma unroll
        for (int j = 0; j < 8; ++j) o[j] = f2bf(a[j] * inv);
        __builtin_nontemporal_store(o, (ushort8v*)(agg + (long long)wid * 256 + c8));
    }
}

// ================= GEMM 1: h1 = relu(feat@Ws1 + agg@Wn1 + b1) =================
// tile 128 rows x 256 cols, 8 waves (2 x 4), BK=32, two A-passes. LDS-staged A and B.
__global__ __launch_bounds__(512)
void gemm1_kernel(const unsigned short* __restrict__ A,  const unsigned short* __restrict__ WT,
                  const unsigned short* __restrict__ A2, const unsigned short* __restrict__ WT2,
                  const float* __restrict__ bias, unsigned short* __restrict__ C, int M)
{
    const int K = 256;
    __shared__ __align__(16) char lds[2][24576];   // A: [0,8192)  B: [8192,24576)

    const int tid = threadIdx.x;
    const int wid = tid >> 6, lane = tid & 63;
    const int l15 = lane & 15, lg = lane >> 4;
    const int wr = wid >> 2, wc = wid & 3;
    const int row0 = blockIdx.x * 128;

    long long asrc; int adst;
    {
        int c = tid, r = c >> 2, s = c & 3;
        int kc = s ^ ((r >> 1) & 3);
        asrc = (long long)min(row0 + r, M - 1) * K + kc * 8;
        adst = c * 16;
    }
    long long bsrc[2]; int bdst[2];
#pragma unroll
    for (int i = 0; i < 2; ++i) {
        int c = wid * 128 + i * 64 + lane, r = c >> 2, s = c & 3;
        int kc = s ^ ((r >> 1) & 3);
        bsrc[i] = (long long)r * K + kc * 8;
        bdst[i] = 8192 + c * 16;
    }

    const int slot = (lg ^ ((l15 >> 1) & 3)) * 16;
    int aoff[4], boff[4];
#pragma unroll
    for (int m = 0; m < 4; ++m) aoff[m] = (wr * 64 + m * 16 + l15) * 64 + slot;
#pragma unroll
    for (int n = 0; n < 4; ++n) boff[n] = 8192 + (wc * 64 + n * 16 + l15) * 64 + slot;

    f32x4 acc[4][4] = {};

    auto stage = [&](int buf, int t) {
        const unsigned short* Ap = (t >= 8) ? A2 : A;
        const unsigned short* Wp = (t >= 8) ? WT2 : WT;
        int k0 = (t & 7) * 32;
        gload16(Ap + asrc + k0, &lds[buf][adst]);
        gload16(Wp + bsrc[0] + k0, &lds[buf][bdst[0]]);
        gload16(Wp + bsrc[1] + k0, &lds[buf][bdst[1]]);
    };

    stage(0, 0);
    __syncthreads();

    for (int t = 0; t < 16; ++t) {
        const int cur = t & 1;
        if (t + 1 < 16) stage(cur ^ 1, t + 1);
        const char* L = lds[cur];
        bf16x8 af[4], bfr[4];
#pragma unroll
        for (int m = 0; m < 4; ++m) af[m]  = *(const bf16x8*)(L + aoff[m]);
#pragma unroll
        for (int n = 0; n < 4; ++n) bfr[n] = *(const bf16x8*)(L + boff[n]);
#pragma unroll
        for (int m = 0; m < 4; ++m)
#pragma unroll
            for (int n = 0; n < 4; ++n)
                acc[m][n] = __builtin_amdgcn_mfma_f32_16x16x32_bf16(af[m], bfr[n], acc[m][n], 0, 0, 0);
        __syncthreads();
    }

#pragma unroll
    for (int m = 0; m < 4; ++m) {
#pragma unroll
        for (int rr = 0; rr < 4; ++rr) {
            int grow = row0 + wr * 64 + m * 16 + lg * 4 + rr;
            if (grow >= M) continue;
#pragma unroll
            for (int n = 0; n < 4; ++n) {
                int gcol = wc * 64 + n * 16 + l15;
                float v = fmaxf(acc[m][n][rr] + bias[gcol], 0.f);
                C[(long long)grow * 256 + gcol] = f2bf(v);
            }
        }
    }
}

// ====== GEMM 23: [p2 | self2+b2] = h1 @ wcat^T  (single K=256 pass, split epilogue) ======
__global__ __launch_bounds__(512)
void gemm23_kernel(const unsigned short* __restrict__ A, const unsigned short* __restrict__ WT,
                   const float* __restrict__ b2,
                   unsigned short* __restrict__ p2, unsigned short* __restrict__ self2, int M)
{
    const int K = 256;
    __shared__ __align__(16) char lds[2][24576];   // A: [0,8192)  B: [8192,24576)

    const int tid = threadIdx.x;
    const int wid = tid >> 6, lane = tid & 63;
    const int l15 = lane & 15, lg = lane >> 4;
    const int wr = wid >> 2, wc = wid & 3;
    const int row0 = blockIdx.x * 128;

    long long asrc; int adst;
    {
        int c = tid, r = c >> 2, s = c & 3;
        int kc = s ^ ((r >> 1) & 3);
        asrc = (long long)min(row0 + r, M - 1) * K + kc * 8;
        adst = c * 16;
    }
    long long bsrc[2]; int bdst[2];
#pragma unroll
    for (int i = 0; i < 2; ++i) {
        int c = wid * 128 + i * 64 + lane, r = c >> 2, s = c & 3;
        int kc = s ^ ((r >> 1) & 3);
        bsrc[i] = (long long)r * K + kc * 8;
        bdst[i] = 8192 + c * 16;
    }

    const int slot = (lg ^ ((l15 >> 1) & 3)) * 16;
    int aoff[4], boff[4];
#pragma unroll
    for (int m = 0; m < 4; ++m) aoff[m] = (wr * 64 + m * 16 + l15) * 64 + slot;
#pragma unroll
    for (int n = 0; n < 4; ++n) boff[n] = 8192 + (wc * 64 + n * 16 + l15) * 64 + slot;

    f32x4 acc[4][4] = {};

    auto stage = [&](int buf, int t) {
        int k0 = t * 32;
        gload16(A  + asrc + k0, &lds[buf][adst]);
        gload16(WT + bsrc[0] + k0, &lds[buf][bdst[0]]);
        gload16(WT + bsrc[1] + k0, &lds[buf][bdst[1]]);
    };

    stage(0, 0);
    __syncthreads();

    for (int t = 0; t < 8; ++t) {
        const int cur = t & 1;
        if (t + 1 < 8) stage(cur ^ 1, t + 1);
        const char* L = lds[cur];
        bf16x8 af[4], bfr[4];
#pragma unroll
        for (int m = 0; m < 4; ++m) af[m]  = *(const bf16x8*)(L + aoff[m]);
#pragma unroll
        for (int n = 0; n < 4; ++n) bfr[n] = *(const bf16x8*)(L + boff[n]);
#pragma unroll
        for (int m = 0; m < 4; ++m)
#pragma unroll
            for (int n = 0; n < 4; ++n)
                acc[m][n] = __builtin_amdgcn_mfma_f32_16x16x32_bf16(af[m], bfr[n], acc[m][n], 0, 0, 0);
        __syncthreads();
    }

    // epilogue: cols 0-127 (wc 0/1) -> p2; cols 128-255 (wc 2/3) -> self2 (+b2)
    if (wc < 2) {
#pragma unroll
        for (int m = 0; m < 4; ++m)
#pragma unroll
            for (int rr = 0; rr < 4; ++rr) {
                int grow = row0 + wr * 64 + m * 16 + lg * 4 + rr;
                if (grow >= M) continue;
#pragma unroll
                for (int n = 0; n < 4; ++n) {
                    int col = wc * 64 + n * 16 + l15;
                    __builtin_nontemporal_store(f2bf(acc[m][n][rr]),
                        &p2[(long long)grow * 128 + col]);
                }
            }
    } else {
        float bv[4];
#pragma unroll
        for (int n = 0; n < 4; ++n) bv[n] = b2[(wc - 2) * 64 + n * 16 + l15];
#pragma unroll
        for (int m = 0; m < 4; ++m)
#pragma unroll
            for (int rr = 0; rr < 4; ++rr) {
                int grow = row0 + wr * 64 + m * 16 + lg * 4 + rr;
                if (grow >= M) continue;
#pragma unroll
                for (int n = 0; n < 4; ++n) {
                    int col = (wc - 2) * 64 + n * 16 + l15;
                    __builtin_nontemporal_store(f2bf(acc[m][n][rr] + bv[n]),
                        &self2[(long long)grow * 128 + col]);
                }
            }
    }
}

// ===== gather128 + final: out = normalize(relu(self2 + mean_nb(p2))) , one wave/node =====
__global__ void gather_final_kernel(const unsigned short* __restrict__ p2, const int* __restrict__ off,
                                    const int* __restrict__ csr, const unsigned short* __restrict__ self2,
                                    float* __restrict__ out, int N) {
    int wid  = (int)((blockIdx.x * (long long)blockDim.x + threadIdx.x) >> 6);
    int lane = threadIdx.x & 63;
    if (wid >= N) return;
    int start = off[wid], end = off[wid + 1];
    const int g  = lane >> 4;            // 0..3: which row of the quad
    const int c8 = (lane & 15) * 8;      // 8 cols per lane -> 128
    float a[8] = {};
    int e = start;
    for (; e + 7 < end; e += 8) {        // 2 quads in flight
        int s0 = csr[e + g], s1 = csr[e + 4 + g];
        ushort8v v0 = *(const ushort8v*)(p2 + (long long)s0 * 128 + c8);
        ushort8v v1 = *(const ushort8v*)(p2 + (long long)s1 * 128 + c8);
#pragma unroll
        for (int j = 0; j < 8; ++j) a[j] += bf2f(v0[j]) + bf2f(v1[j]);
    }
    for (; e < end; e += 4) {
        int idx = e + g;
        if (idx < end) {
            int s = csr[idx];
            ushort8v v = *(const ushort8v*)(p2 + (long long)s * 128 + c8);
#pragma unroll
            for (int j = 0; j < 8; ++j) a[j] += bf2f(v[j]);
        }
    }
#pragma unroll
    for (int j = 0; j < 8; ++j) {
        a[j] += __shfl_xor(a[j], 16);
        a[j] += __shfl_xor(a[j], 32);
    }
    float invd = 1.0f / (float)max(end - start, 1);
    ushort8v sv = *(const ushort8v*)(self2 + (long long)wid * 128 + c8);
    float v[8];
    float ss = 0.f;
#pragma unroll
    for (int j = 0; j < 8; ++j) {
        v[j] = fmaxf(bf2f(sv[j]) + a[j] * invd, 0.f);
        ss += v[j] * v[j];
    }
    ss += __shfl_xor(ss, 1);
    ss += __shfl_xor(ss, 2);
    ss += __shfl_xor(ss, 4);
    ss += __shfl_xor(ss, 8);
    float inv = 1.0f / fmaxf(sqrtf(ss), 1e-12f);
    if (g == 0) {
        f32x4 o0 = { v[0] * inv, v[1] * inv, v[2] * inv, v[3] * inv };
        f32x4 o1 = { v[4] * inv, v[5] * inv, v[6] * inv, v[7] * inv };
        float* dstp = out + (long long)wid * 128 + c8;
        __builtin_nontemporal_store(o0, (f32x4*)dstp);
        __builtin_nontemporal_store(o1, (f32x4*)(dstp + 4));
    }
}

extern "C" void kernel_launch(void* const* d_in, const int* in_sizes, int n_in,
                              void* d_out, int out_size, void* d_ws, size_t ws_size,
                              hipStream_t stream) {
    const float* feat     = (const float*)d_in[0];
    const int*   src      = (const int*)  d_in[1];
    const int*   dst      = (const int*)  d_in[2];
    const float* w_self1  = (const float*)d_in[3];
    const float* w_neigh1 = (const float*)d_in[4];
    const float* b1       = (const float*)d_in[5];
    const float* w_self2  = (const float*)d_in[6];
    const float* w_neigh2 = (const float*)d_in[7];
    const float* b2       = (const float*)d_in[8];
    float* out = (float*)d_out;

    const int N = in_sizes[0] / DIN;    // 100000
    const int E = in_sizes[1];          // 800000

    char* ws = (char*)d_ws;
    auto a4k = [](size_t x) { return (x + 4095) & ~(size_t)4095; };
    size_t o = 0;
    int* cnt  = (int*)(ws + o); o += a4k((size_t)N * 4);
    int* off  = (int*)(ws + o); o += a4k((size_t)(N + 1) * 4);
    int* part = (int*)(ws + o); o += a4k(1024);
    int* csr  = (int*)(ws + o); o += a4k((size_t)E * 4);
    unsigned short* ws1t = (unsigned short*)(ws + o); o += a4k((size_t)DIN * DH * 2);
    unsigned short* wn1t = (unsigned short*)(ws + o); o += a4k((size_t)DIN * DH * 2);
    unsigned short* wcat = (unsigned short*)(ws + o); o += a4k((size_t)256 * 256 * 2);
    unsigned short* featb = (unsigned short*)(ws + o); o += a4k((size_t)N * DIN * 2);  // reused: p2b
    unsigned short* aggb  = (unsigned short*)(ws + o); o += a4k((size_t)N * DIN * 2);  // reused: self2b
    unsigned short* h1b   = (unsigned short*)(ws + o); o += a4k((size_t)N * DH * 2);

    unsigned short* p2b    = featb;   // dead after gemm1
    unsigned short* self2b = aggb;    // dead after gemm1

    const int nblk = (N + 1023) / 1024;

    // ---- prep: cvt + wtrans + count (cnt zeroed first) ----
    hipMemsetAsync(cnt, 0, (size_t)N * 4, stream);
    long long n8 = (long long)N * DIN / 8;
    const int bCvt = (int)((n8 + 255) / 256);       // 12500
    const int bWt  = 768;
    const int bCnt = (E + 255) / 256;               // 3125
    prep_kernel<<<bCvt + bWt + bCnt, 256, 0, stream>>>(
        feat, featb, n8, w_self1, w_neigh1, w_self2, w_neigh2,
        ws1t, wn1t, wcat, dst, cnt, E, bCvt, bWt);

    // ---- CSR scan + fill ----
    block_sums_kernel<<<nblk, 256, 0, stream>>>(cnt, part, N);
    scan_partials_kernel<<<1, 256, 0, stream>>>(part, nblk);
    scan_block_kernel<<<nblk, 256, 0, stream>>>(cnt, part, off, N, E);   // also inits cursor (cnt)
    fill_csr_kernel<<<(E + 255) / 256, 256, 0, stream>>>(src, dst, cnt, csr, E);

    const int mblk = (N + 127) / 128;   // 782

    // ---- layer 1 ----
    gather_mean256_kernel<<<(N + 3) / 4, 256, 0, stream>>>(featb, off, csr, aggb, N);
    gemm1_kernel<<<mblk, 512, 0, stream>>>(featb, ws1t, aggb, wn1t, b1, h1b, N);

    // ---- layer 2: both projections in one pass, then fused gather+norm ----
    gemm23_kernel<<<mblk, 512, 0, stream>>>(h1b, wcat, b2, p2b, self2b, N);
    gather_final_kernel<<<(N + 3) / 4, 256, 0, stream>>>(p2b, off, csr, self2b, out, N);
}

// Round 10
// 306.844 us; speedup vs baseline: 1.1353x; 1.0173x over previous
//
#include <hip/hip_runtime.h>

#define DIN 256
#define DH  256
#define DOUT 128

typedef __attribute__((ext_vector_type(8))) short bf16x8;
typedef __attribute__((ext_vector_type(4))) float f32x4;
typedef __attribute__((ext_vector_type(2))) float f32x2;
typedef __attribute__((ext_vector_type(8))) unsigned short ushort8v;
typedef __attribute__((ext_vector_type(2))) unsigned int uint2v;
typedef __attribute__((ext_vector_type(4))) unsigned int uint4v;

static __device__ __forceinline__ unsigned short f2bf(float x) {
    unsigned u = __float_as_uint(x);
    u += 0x7fffu + ((u >> 16) & 1u);          // round-to-nearest-even
    return (unsigned short)(u >> 16);
}
static __device__ __forceinline__ float bf2f(unsigned short h) {
    return __uint_as_float(((unsigned)h) << 16);
}

static __device__ __forceinline__ void gload16(const unsigned short* g, void* l) {
    __builtin_amdgcn_global_load_lds(
        (const __attribute__((address_space(1))) unsigned int*)g,
        (__attribute__((address_space(3))) unsigned int*)l,
        16, 0, 0);
}

// ======== prep: feat->bf16 + fp8 | weight transposes | degree count ========
__global__ void prep_kernel(const float* __restrict__ feat, unsigned short* __restrict__ featb,
                            unsigned int* __restrict__ feat8, long long n8,
                            const float* __restrict__ w_self1, const float* __restrict__ w_neigh1,
                            const float* __restrict__ w_self2, const float* __restrict__ w_neigh2,
                            unsigned short* __restrict__ ws1t, unsigned short* __restrict__ wn1t,
                            unsigned short* __restrict__ wcat,
                            const int* __restrict__ dst, int* __restrict__ cnt, int E,
                            int bCvt, int bWt) {
    int b = blockIdx.x;
    if (b < bCvt) {
        long long i = b * 256LL + threadIdx.x;
        if (i >= n8) return;
        const f32x4* p = (const f32x4*)(feat + i * 8);
        f32x4 a = __builtin_nontemporal_load(p);
        f32x4 c = __builtin_nontemporal_load(p + 1);
        ushort8v o;
        o[0] = f2bf(a[0]); o[1] = f2bf(a[1]); o[2] = f2bf(a[2]); o[3] = f2bf(a[3]);
        o[4] = f2bf(c[0]); o[5] = f2bf(c[1]); o[6] = f2bf(c[2]); o[7] = f2bf(c[3]);
        *(ushort8v*)(featb + i * 8) = o;
        // fp8 e4m3 mirror for the gather (bytes in order f0..f7)
        int u0 = __builtin_amdgcn_cvt_pk_fp8_f32(a[0], a[1], 0, 0);
        u0     = __builtin_amdgcn_cvt_pk_fp8_f32(a[2], a[3], u0, 1);
        int u1 = __builtin_amdgcn_cvt_pk_fp8_f32(c[0], c[1], 0, 0);
        u1     = __builtin_amdgcn_cvt_pk_fp8_f32(c[2], c[3], u1, 1);
        uint2v q = { (unsigned)u0, (unsigned)u1 };
        __builtin_nontemporal_store(q, (uint2v*)(feat8 + i * 2));
    } else if (b < bCvt + bWt) {
        int idx = (b - bCvt) * 256 + threadIdx.x;
        if (idx < 65536) {                      // ws1t[n][k] = w_self1[k][n]
            int nn = idx >> 8, k = idx & 255;
            ws1t[idx] = f2bf(w_self1[k * 256 + nn]);
        } else if (idx < 131072) {              // wn1t
            int j = idx - 65536; int nn = j >> 8, k = j & 255;
            wn1t[j] = f2bf(w_neigh1[k * 256 + nn]);
        } else if (idx < 163840) {              // wcat rows 0..127 = wn2^T
            int j = idx - 131072; int nn = j >> 8, k = j & 255;
            wcat[j] = f2bf(w_neigh2[k * 128 + nn]);
        } else if (idx < 196608) {              // wcat rows 128..255 = ws2^T
            int j = idx - 163840; int nn = j >> 8, k = j & 255;
            wcat[32768 + j] = f2bf(w_self2[k * 128 + nn]);
        }
    } else {
        int e = (b - bCvt - bWt) * 256 + threadIdx.x;
        if (e < E) atomicAdd(&cnt[dst[e]], 1);
    }
}

// ================= CSR scan / fill =================
__global__ void block_sums_kernel(const int* __restrict__ cnt, int* __restrict__ partial, int N) {
    __shared__ int sdata[256];
    int t = threadIdx.x;
    int base = blockIdx.x * 1024;
    int s = 0;
#pragma unroll
    for (int j = 0; j < 4; ++j) {
        int i = base + t * 4 + j;
        if (i < N) s += cnt[i];
    }
    sdata[t] = s; __syncthreads();
    for (int o = 128; o; o >>= 1) {
        if (t < o) sdata[t] += sdata[t + o];
        __syncthreads();
    }
    if (t == 0) partial[blockIdx.x] = sdata[0];
}

__global__ void scan_partials_kernel(int* __restrict__ partial, int nb) {
    __shared__ int sdata[256];
    int t = threadIdx.x;
    int v = (t < nb) ? partial[t] : 0;
    sdata[t] = v; __syncthreads();
    for (int o = 1; o < 256; o <<= 1) {
        int y = (t >= o) ? sdata[t - o] : 0;
        __syncthreads();
        sdata[t] += y;
        __syncthreads();
    }
    if (t < nb) partial[t] = sdata[t] - v;
}

// writes offsets AND initializes the fill-cursor (same values)
__global__ void scan_block_kernel(int* __restrict__ cnt, const int* __restrict__ partial,
                                  int* __restrict__ off, int N, int E) {
    __shared__ int sdata[256];
    int b = blockIdx.x, t = threadIdx.x;
    int base = b * 1024;
    int vals[4]; int local = 0;
#pragma unroll
    for (int j = 0; j < 4; ++j) {
        int i = base + t * 4 + j;
        vals[j] = (i < N) ? cnt[i] : 0;
        local += vals[j];
    }
    sdata[t] = local; __syncthreads();
    for (int o = 1; o < 256; o <<= 1) {
        int y = (t >= o) ? sdata[t - o] : 0;
        __syncthreads();
        sdata[t] += y;
        __syncthreads();
    }
    int run = sdata[t] - local + partial[b];
#pragma unroll
    for (int j = 0; j < 4; ++j) {
        int i = base + t * 4 + j;
        if (i < N) { off[i] = run; cnt[i] = run; }   // cnt becomes cursor
        run += vals[j];
    }
    if (b == 0 && t == 0) off[N] = E;
}

__global__ void fill_csr_kernel(const int* __restrict__ src, const int* __restrict__ dst,
                                int* __restrict__ cursor, int* __restrict__ csr, int E) {
    int e = blockIdx.x * blockDim.x + threadIdx.x;
    if (e < E) {
        int d = dst[e];
        int p = atomicAdd(&cursor[d], 1);
        csr[p] = src[e];
    }
}

// ===== gather-mean D=256 from fp8: 4 rows per load (16 lanes each, 16B/lane) =====
__global__ void gather_mean256_kernel(const unsigned int* __restrict__ feat8, const int* __restrict__ off,
                                      const int* __restrict__ csr, unsigned short* __restrict__ agg, int N) {
    int wid  = (int)((blockIdx.x * (long long)blockDim.x + threadIdx.x) >> 6);
    int lane = threadIdx.x & 63;
    if (wid >= N) return;
    int start = off[wid], end = off[wid + 1];
    const int g   = lane >> 4;           // 0..3: which row of the quad
    const int cl  = lane & 15;           // 16 fp8 cols per lane -> 256
    float a[16] = {};
    int e = start;
    for (; e + 7 < end; e += 8) {        // 2 quads in flight
        int s0 = csr[e + g], s1 = csr[e + 4 + g];
        uint4v v0 = *(const uint4v*)(feat8 + (long long)s0 * 64 + cl * 4);
        uint4v v1 = *(const uint4v*)(feat8 + (long long)s1 * 64 + cl * 4);
#pragma unroll
        for (int d = 0; d < 4; ++d) {
            f32x2 p0 = __builtin_amdgcn_cvt_pk_f32_fp8((int)v0[d], false);
            f32x2 p1 = __builtin_amdgcn_cvt_pk_f32_fp8((int)v0[d], true);
            f32x2 q0 = __builtin_amdgcn_cvt_pk_f32_fp8((int)v1[d], false);
            f32x2 q1 = __builtin_amdgcn_cvt_pk_f32_fp8((int)v1[d], true);
            a[d * 4 + 0] += p0[0] + q0[0];
            a[d * 4 + 1] += p0[1] + q0[1];
            a[d * 4 + 2] += p1[0] + q1[0];
            a[d * 4 + 3] += p1[1] + q1[1];
        }
    }
    for (; e < end; e += 4) {
        int idx = e + g;
        if (idx < end) {
            int s = csr[idx];
            uint4v v = *(const uint4v*)(feat8 + (long long)s * 64 + cl * 4);
#pragma unroll
            for (int d = 0; d < 4; ++d) {
                f32x2 p0 = __builtin_amdgcn_cvt_pk_f32_fp8((int)v[d], false);
                f32x2 p1 = __builtin_amdgcn_cvt_pk_f32_fp8((int)v[d], true);
                a[d * 4 + 0] += p0[0];
                a[d * 4 + 1] += p0[1];
                a[d * 4 + 2] += p1[0];
                a[d * 4 + 3] += p1[1];
            }
        }
    }
#pragma unroll
    for (int j = 0; j < 16; ++j) {
        a[j] += __shfl_xor(a[j], 16);
        a[j] += __shfl_xor(a[j], 32);
    }
    if (g == 0) {
        float inv = 1.0f / (float)max(end - start, 1);
        ushort8v o0, o1;
#pragma unroll
        for (int j = 0; j < 8; ++j) { o0[j] = f2bf(a[j] * inv); o1[j] = f2bf(a[8 + j] * inv); }
        unsigned short* dstp = agg + (long long)wid * 256 + cl * 16;
        __builtin_nontemporal_store(o0, (ushort8v*)dstp);
        __builtin_nontemporal_store(o1, (ushort8v*)(dstp + 8));
    }
}

// ================= GEMM 1: h1 = relu(feat@Ws1 + agg@Wn1 + b1) =================
// tile 128 rows x 256 cols, 8 waves (2 x 4), BK=32, two A-passes. LDS-staged A and B.
__global__ __launch_bounds__(512)
void gemm1_kernel(const unsigned short* __restrict__ A,  const unsigned short* __restrict__ WT,
                  const unsigned short* __restrict__ A2, const unsigned short* __restrict__ WT2,
                  const float* __restrict__ bias, unsigned short* __restrict__ C, int M)
{
    const int K = 256;
    __shared__ __align__(16) char lds[2][24576];   // A: [0,8192)  B: [8192,24576)

    const int tid = threadIdx.x;
    const int wid = tid >> 6, lane = tid & 63;
    const int l15 = lane & 15, lg = lane >> 4;
    const int wr = wid >> 2, wc = wid & 3;
    const int row0 = blockIdx.x * 128;

    long long asrc; int adst;
    {
        int c = tid, r = c >> 2, s = c & 3;
        int kc = s ^ ((r >> 1) & 3);
        asrc = (long long)min(row0 + r, M - 1) * K + kc * 8;
        adst = c * 16;
    }
    long long bsrc[2]; int bdst[2];
#pragma unroll
    for (int i = 0; i < 2; ++i) {
        int c = wid * 128 + i * 64 + lane, r = c >> 2, s = c & 3;
        int kc = s ^ ((r >> 1) & 3);
        bsrc[i] = (long long)r * K + kc * 8;
        bdst[i] = 8192 + c * 16;
    }

    const int slot = (lg ^ ((l15 >> 1) & 3)) * 16;
    int aoff[4], boff[4];
#pragma unroll
    for (int m = 0; m < 4; ++m) aoff[m] = (wr * 64 + m * 16 + l15) * 64 + slot;
#pragma unroll
    for (int n = 0; n < 4; ++n) boff[n] = 8192 + (wc * 64 + n * 16 + l15) * 64 + slot;

    f32x4 acc[4][4] = {};

    auto stage = [&](int buf, int t) {
        const unsigned short* Ap = (t >= 8) ? A2 : A;
        const unsigned short* Wp = (t >= 8) ? WT2 : WT;
        int k0 = (t & 7) * 32;
        gload16(Ap + asrc + k0, &lds[buf][adst]);
        gload16(Wp + bsrc[0] + k0, &lds[buf][bdst[0]]);
        gload16(Wp + bsrc[1] + k0, &lds[buf][bdst[1]]);
    };

    stage(0, 0);
    __syncthreads();

    for (int t = 0; t < 16; ++t) {
        const int cur = t & 1;
        if (t + 1 < 16) stage(cur ^ 1, t + 1);
        const char* L = lds[cur];
        bf16x8 af[4], bfr[4];
#pragma unroll
        for (int m = 0; m < 4; ++m) af[m]  = *(const bf16x8*)(L + aoff[m]);
#pragma unroll
        for (int n = 0; n < 4; ++n) bfr[n] = *(const bf16x8*)(L + boff[n]);
#pragma unroll
        for (int m = 0; m < 4; ++m)
#pragma unroll
            for (int n = 0; n < 4; ++n)
                acc[m][n] = __builtin_amdgcn_mfma_f32_16x16x32_bf16(af[m], bfr[n], acc[m][n], 0, 0, 0);
        __syncthreads();
    }

#pragma unroll
    for (int m = 0; m < 4; ++m) {
#pragma unroll
        for (int rr = 0; rr < 4; ++rr) {
            int grow = row0 + wr * 64 + m * 16 + lg * 4 + rr;
            if (grow >= M) continue;
#pragma unroll
            for (int n = 0; n < 4; ++n) {
                int gcol = wc * 64 + n * 16 + l15;
                float v = fmaxf(acc[m][n][rr] + bias[gcol], 0.f);
                C[(long long)grow * 256 + gcol] = f2bf(v);
            }
        }
    }
}

// ====== GEMM 23: [p2 | self2+b2] = h1 @ wcat^T  (single K=256 pass, split epilogue) ======
__global__ __launch_bounds__(512)
void gemm23_kernel(const unsigned short* __restrict__ A, const unsigned short* __restrict__ WT,
                   const float* __restrict__ b2,
                   unsigned short* __restrict__ p2, unsigned short* __restrict__ self2, int M)
{
    const int K = 256;
    __shared__ __align__(16) char lds[2][24576];   // A: [0,8192)  B: [8192,24576)

    const int tid = threadIdx.x;
    const int wid = tid >> 6, lane = tid & 63;
    const int l15 = lane & 15, lg = lane >> 4;
    const int wr = wid >> 2, wc = wid & 3;
    const int row0 = blockIdx.x * 128;

    long long asrc; int adst;
    {
        int c = tid, r = c >> 2, s = c & 3;
        int kc = s ^ ((r >> 1) & 3);
        asrc = (long long)min(row0 + r, M - 1) * K + kc * 8;
        adst = c * 16;
    }
    long long bsrc[2]; int bdst[2];
#pragma unroll
    for (int i = 0; i < 2; ++i) {
        int c = wid * 128 + i * 64 + lane, r = c >> 2, s = c & 3;
        int kc = s ^ ((r >> 1) & 3);
        bsrc[i] = (long long)r * K + kc * 8;
        bdst[i] = 8192 + c * 16;
    }

    const int slot = (lg ^ ((l15 >> 1) & 3)) * 16;
    int aoff[4], boff[4];
#pragma unroll
    for (int m = 0; m < 4; ++m) aoff[m] = (wr * 64 + m * 16 + l15) * 64 + slot;
#pragma unroll
    for (int n = 0; n < 4; ++n) boff[n] = 8192 + (wc * 64 + n * 16 + l15) * 64 + slot;

    f32x4 acc[4][4] = {};

    auto stage = [&](int buf, int t) {
        int k0 = t * 32;
        gload16(A  + asrc + k0, &lds[buf][adst]);
        gload16(WT + bsrc[0] + k0, &lds[buf][bdst[0]]);
        gload16(WT + bsrc[1] + k0, &lds[buf][bdst[1]]);
    };

    stage(0, 0);
    __syncthreads();

    for (int t = 0; t < 8; ++t) {
        const int cur = t & 1;
        if (t + 1 < 8) stage(cur ^ 1, t + 1);
        const char* L = lds[cur];
        bf16x8 af[4], bfr[4];
#pragma unroll
        for (int m = 0; m < 4; ++m) af[m]  = *(const bf16x8*)(L + aoff[m]);
#pragma unroll
        for (int n = 0; n < 4; ++n) bfr[n] = *(const bf16x8*)(L + boff[n]);
#pragma unroll
        for (int m = 0; m < 4; ++m)
#pragma unroll
            for (int n = 0; n < 4; ++n)
                acc[m][n] = __builtin_amdgcn_mfma_f32_16x16x32_bf16(af[m], bfr[n], acc[m][n], 0, 0, 0);
        __syncthreads();
    }

    // epilogue: cols 0-127 (wc 0/1) -> p2; cols 128-255 (wc 2/3) -> self2 (+b2)
    if (wc < 2) {
#pragma unroll
        for (int m = 0; m < 4; ++m)
#pragma unroll
            for (int rr = 0; rr < 4; ++rr) {
                int grow = row0 + wr * 64 + m * 16 + lg * 4 + rr;
                if (grow >= M) continue;
#pragma unroll
                for (int n = 0; n < 4; ++n) {
                    int col = wc * 64 + n * 16 + l15;
                    __builtin_nontemporal_store(f2bf(acc[m][n][rr]),
                        &p2[(long long)grow * 128 + col]);
                }
            }
    } else {
        float bv[4];
#pragma unroll
        for (int n = 0; n < 4; ++n) bv[n] = b2[(wc - 2) * 64 + n * 16 + l15];
#pragma unroll
        for (int m = 0; m < 4; ++m)
#pragma unroll
            for (int rr = 0; rr < 4; ++rr) {
                int grow = row0 + wr * 64 + m * 16 + lg * 4 + rr;
                if (grow >= M) continue;
#pragma unroll
                for (int n = 0; n < 4; ++n) {
                    int col = (wc - 2) * 64 + n * 16 + l15;
                    __builtin_nontemporal_store(f2bf(acc[m][n][rr] + bv[n]),
                        &self2[(long long)grow * 128 + col]);
                }
            }
    }
}

// ===== gather128 + final: out = normalize(relu(self2 + mean_nb(p2))) , one wave/node =====
__global__ void gather_final_kernel(const unsigned short* __restrict__ p2, const int* __restrict__ off,
                                    const int* __restrict__ csr, const unsigned short* __restrict__ self2,
                                    float* __restrict__ out, int N) {
    int wid  = (int)((blockIdx.x * (long long)blockDim.x + threadIdx.x) >> 6);
    int lane = threadIdx.x & 63;
    if (wid >= N) return;
    int start = off[wid], end = off[wid + 1];
    const int g  = lane >> 4;            // 0..3: which row of the quad
    const int c8 = (lane & 15) * 8;      // 8 cols per lane -> 128
    float a[8] = {};
    int e = start;
    for (; e + 7 < end; e += 8) {        // 2 quads in flight
        int s0 = csr[e + g], s1 = csr[e + 4 + g];
        ushort8v v0 = *(const ushort8v*)(p2 + (long long)s0 * 128 + c8);
        ushort8v v1 = *(const ushort8v*)(p2 + (long long)s1 * 128 + c8);
#pragma unroll
        for (int j = 0; j < 8; ++j) a[j] += bf2f(v0[j]) + bf2f(v1[j]);
    }
    for (; e < end; e += 4) {
        int idx = e + g;
        if (idx < end) {
            int s = csr[idx];
            ushort8v v = *(const ushort8v*)(p2 + (long long)s * 128 + c8);
#pragma unroll
            for (int j = 0; j < 8; ++j) a[j] += bf2f(v[j]);
        }
    }
#pragma unroll
    for (int j = 0; j < 8; ++j) {
        a[j] += __shfl_xor(a[j], 16);
        a[j] += __shfl_xor(a[j], 32);
    }
    float invd = 1.0f / (float)max(end - start, 1);
    ushort8v sv = *(const ushort8v*)(self2 + (long long)wid * 128 + c8);
    float v[8];
    float ss = 0.f;
#pragma unroll
    for (int j = 0; j < 8; ++j) {
        v[j] = fmaxf(bf2f(sv[j]) + a[j] * invd, 0.f);
        ss += v[j] * v[j];
    }
    ss += __shfl_xor(ss, 1);
    ss += __shfl_xor(ss, 2);
    ss += __shfl_xor(ss, 4);
    ss += __shfl_xor(ss, 8);
    float inv = 1.0f / fmaxf(sqrtf(ss), 1e-12f);
    if (g == 0) {
        f32x4 o0 = { v[0] * inv, v[1] * inv, v[2] * inv, v[3] * inv };
        f32x4 o1 = { v[4] * inv, v[5] * inv, v[6] * inv, v[7] * inv };
        float* dstp = out + (long long)wid * 128 + c8;
        __builtin_nontemporal_store(o0, (f32x4*)dstp);
        __builtin_nontemporal_store(o1, (f32x4*)(dstp + 4));
    }
}

extern "C" void kernel_launch(void* const* d_in, const int* in_sizes, int n_in,
                              void* d_out, int out_size, void* d_ws, size_t ws_size,
                              hipStream_t stream) {
    const float* feat     = (const float*)d_in[0];
    const int*   src      = (const int*)  d_in[1];
    const int*   dst      = (const int*)  d_in[2];
    const float* w_self1  = (const float*)d_in[3];
    const float* w_neigh1 = (const float*)d_in[4];
    const float* b1       = (const float*)d_in[5];
    const float* w_self2  = (const float*)d_in[6];
    const float* w_neigh2 = (const float*)d_in[7];
    const float* b2       = (const float*)d_in[8];
    float* out = (float*)d_out;

    const int N = in_sizes[0] / DIN;    // 100000
    const int E = in_sizes[1];          // 800000

    char* ws = (char*)d_ws;
    auto a4k = [](size_t x) { return (x + 4095) & ~(size_t)4095; };
    size_t o = 0;
    int* cnt  = (int*)(ws + o); o += a4k((size_t)N * 4);
    int* off  = (int*)(ws + o); o += a4k((size_t)(N + 1) * 4);
    int* part = (int*)(ws + o); o += a4k(1024);
    int* csr  = (int*)(ws + o); o += a4k((size_t)E * 4);
    unsigned short* ws1t = (unsigned short*)(ws + o); o += a4k((size_t)DIN * DH * 2);
    unsigned short* wn1t = (unsigned short*)(ws + o); o += a4k((size_t)DIN * DH * 2);
    unsigned short* wcat = (unsigned short*)(ws + o); o += a4k((size_t)256 * 256 * 2);
    unsigned int*   feat8 = (unsigned int*)(ws + o); o += a4k((size_t)N * DIN);       // fp8 mirror
    unsigned short* featb = (unsigned short*)(ws + o); o += a4k((size_t)N * DIN * 2);  // reused: p2b
    unsigned short* aggb  = (unsigned short*)(ws + o); o += a4k((size_t)N * DIN * 2);  // reused: self2b
    unsigned short* h1b   = (unsigned short*)(ws + o); o += a4k((size_t)N * DH * 2);

    unsigned short* p2b    = featb;   // dead after gemm1
    unsigned short* self2b = aggb;    // dead after gemm1

    const int nblk = (N + 1023) / 1024;

    // ---- prep: cvt (bf16 + fp8) + wtrans + count (cnt zeroed first) ----
    hipMemsetAsync(cnt, 0, (size_t)N * 4, stream);
    long long n8 = (long long)N * DIN / 8;
    const int bCvt = (int)((n8 + 255) / 256);       // 12500
    const int bWt  = 768;
    const int bCnt = (E + 255) / 256;               // 3125
    prep_kernel<<<bCvt + bWt + bCnt, 256, 0, stream>>>(
        feat, featb, feat8, n8, w_self1, w_neigh1, w_self2, w_neigh2,
        ws1t, wn1t, wcat, dst, cnt, E, bCvt, bWt);

    // ---- CSR scan + fill ----
    block_sums_kernel<<<nblk, 256, 0, stream>>>(cnt, part, N);
    scan_partials_kernel<<<1, 256, 0, stream>>>(part, nblk);
    scan_block_kernel<<<nblk, 256, 0, stream>>>(cnt, part, off, N, E);   // also inits cursor (cnt)
    fill_csr_kernel<<<(E + 255) / 256, 256, 0, stream>>>(src, dst, cnt, csr, E);

    const int mblk = (N + 127) / 128;   // 782

    // ---- layer 1: fp8 gather + bf16 MFMA GEMM ----
    gather_mean256_kernel<<<(N + 3) / 4, 256, 0, stream>>>(feat8, off, csr, aggb, N);
    gemm1_kernel<<<mblk, 512, 0, stream>>>(featb, ws1t, aggb, wn1t, b1, h1b, N);

    // ---- layer 2: both projections in one pass, then fused gather+norm ----
    gemm23_kernel<<<mblk, 512, 0, stream>>>(h1b, wcat, b2, p2b, self2b, N);
    gather_final_kernel<<<(N + 3) / 4, 256, 0, stream>>>(p2b, off, csr, self2b, out, N);
}

// Round 11
// 294.674 us; speedup vs baseline: 1.1821x; 1.0413x over previous
//
#include <hip/hip_runtime.h>

#define DIN 256
#define DH  256
#define DOUT 128

typedef __attribute__((ext_vector_type(8))) short bf16x8;
typedef __attribute__((ext_vector_type(4))) float f32x4;
typedef __attribute__((ext_vector_type(2))) float f32x2;
typedef __attribute__((ext_vector_type(8))) unsigned short ushort8v;
typedef __attribute__((ext_vector_type(4))) unsigned int uint4v;

static __device__ __forceinline__ unsigned short f2bf(float x) {
    unsigned u = __float_as_uint(x);
    u += 0x7fffu + ((u >> 16) & 1u);          // round-to-nearest-even
    return (unsigned short)(u >> 16);
}
static __device__ __forceinline__ float bf2f(unsigned short h) {
    return __uint_as_float(((unsigned)h) << 16);
}

static __device__ __forceinline__ void gload16(const unsigned short* g, void* l) {
    __builtin_amdgcn_global_load_lds(
        (const __attribute__((address_space(1))) unsigned int*)g,
        (__attribute__((address_space(3))) unsigned int*)l,
        16, 0, 0);
}

// ======== prep: feat->bf16 + fp8 (64B/thread) | weight transposes | degree count ========
__global__ void prep_kernel(const float* __restrict__ feat, unsigned short* __restrict__ featb,
                            unsigned int* __restrict__ feat8, long long n16,
                            const float* __restrict__ w_self1, const float* __restrict__ w_neigh1,
                            const float* __restrict__ w_self2, const float* __restrict__ w_neigh2,
                            unsigned short* __restrict__ ws1t, unsigned short* __restrict__ wn1t,
                            unsigned short* __restrict__ wcat,
                            const int* __restrict__ dst, int* __restrict__ cnt, int E,
                            int bCvt, int bWt) {
    int b = blockIdx.x;
    if (b < bCvt) {
        long long i = b * 256LL + threadIdx.x;
        if (i >= n16) return;
        const f32x4* p = (const f32x4*)(feat + i * 16);
        f32x4 v0 = __builtin_nontemporal_load(p);
        f32x4 v1 = __builtin_nontemporal_load(p + 1);
        f32x4 v2 = __builtin_nontemporal_load(p + 2);
        f32x4 v3 = __builtin_nontemporal_load(p + 3);
        ushort8v o0, o1;
        o0[0] = f2bf(v0[0]); o0[1] = f2bf(v0[1]); o0[2] = f2bf(v0[2]); o0[3] = f2bf(v0[3]);
        o0[4] = f2bf(v1[0]); o0[5] = f2bf(v1[1]); o0[6] = f2bf(v1[2]); o0[7] = f2bf(v1[3]);
        o1[0] = f2bf(v2[0]); o1[1] = f2bf(v2[1]); o1[2] = f2bf(v2[2]); o1[3] = f2bf(v2[3]);
        o1[4] = f2bf(v3[0]); o1[5] = f2bf(v3[1]); o1[6] = f2bf(v3[2]); o1[7] = f2bf(v3[3]);
        *(ushort8v*)(featb + i * 16)     = o0;   // plain store: stays in cache for gemm1
        *(ushort8v*)(featb + i * 16 + 8) = o1;
        // fp8 e4m3 mirror (plain store: must stay L2/L3-hot for the random gather)
        int u0 = __builtin_amdgcn_cvt_pk_fp8_f32(v0[0], v0[1], 0, 0);
        u0     = __builtin_amdgcn_cvt_pk_fp8_f32(v0[2], v0[3], u0, 1);
        int u1 = __builtin_amdgcn_cvt_pk_fp8_f32(v1[0], v1[1], 0, 0);
        u1     = __builtin_amdgcn_cvt_pk_fp8_f32(v1[2], v1[3], u1, 1);
        int u2 = __builtin_amdgcn_cvt_pk_fp8_f32(v2[0], v2[1], 0, 0);
        u2     = __builtin_amdgcn_cvt_pk_fp8_f32(v2[2], v2[3], u2, 1);
        int u3 = __builtin_amdgcn_cvt_pk_fp8_f32(v3[0], v3[1], 0, 0);
        u3     = __builtin_amdgcn_cvt_pk_fp8_f32(v3[2], v3[3], u3, 1);
        uint4v q = { (unsigned)u0, (unsigned)u1, (unsigned)u2, (unsigned)u3 };
        *(uint4v*)(feat8 + i * 4) = q;
    } else if (b < bCvt + bWt) {
        int idx = (b - bCvt) * 256 + threadIdx.x;
        if (idx < 65536) {                      // ws1t[n][k] = w_self1[k][n]
            int nn = idx >> 8, k = idx & 255;
            ws1t[idx] = f2bf(w_self1[k * 256 + nn]);
        } else if (idx < 131072) {              // wn1t
            int j = idx - 65536; int nn = j >> 8, k = j & 255;
            wn1t[j] = f2bf(w_neigh1[k * 256 + nn]);
        } else if (idx < 163840) {              // wcat rows 0..127 = wn2^T
            int j = idx - 131072; int nn = j >> 8, k = j & 255;
            wcat[j] = f2bf(w_neigh2[k * 128 + nn]);
        } else if (idx < 196608) {              // wcat rows 128..255 = ws2^T
            int j = idx - 163840; int nn = j >> 8, k = j & 255;
            wcat[32768 + j] = f2bf(w_self2[k * 128 + nn]);
        }
    } else {
        int e = (b - bCvt - bWt) * 256 + threadIdx.x;
        if (e < E) atomicAdd(&cnt[dst[e]], 1);
    }
}

// ================= CSR scan / fill =================
__global__ void block_sums_kernel(const int* __restrict__ cnt, int* __restrict__ partial, int N) {
    __shared__ int sdata[256];
    int t = threadIdx.x;
    int base = blockIdx.x * 1024;
    int s = 0;
#pragma unroll
    for (int j = 0; j < 4; ++j) {
        int i = base + t * 4 + j;
        if (i < N) s += cnt[i];
    }
    sdata[t] = s; __syncthreads();
    for (int o = 128; o; o >>= 1) {
        if (t < o) sdata[t] += sdata[t + o];
        __syncthreads();
    }
    if (t == 0) partial[blockIdx.x] = sdata[0];
}

__global__ void scan_partials_kernel(int* __restrict__ partial, int nb) {
    __shared__ int sdata[256];
    int t = threadIdx.x;
    int v = (t < nb) ? partial[t] : 0;
    sdata[t] = v; __syncthreads();
    for (int o = 1; o < 256; o <<= 1) {
        int y = (t >= o) ? sdata[t - o] : 0;
        __syncthreads();
        sdata[t] += y;
        __syncthreads();
    }
    if (t < nb) partial[t] = sdata[t] - v;
}

// writes offsets AND initializes the fill-cursor (same values)
__global__ void scan_block_kernel(int* __restrict__ cnt, const int* __restrict__ partial,
                                  int* __restrict__ off, int N, int E) {
    __shared__ int sdata[256];
    int b = blockIdx.x, t = threadIdx.x;
    int base = b * 1024;
    int vals[4]; int local = 0;
#pragma unroll
    for (int j = 0; j < 4; ++j) {
        int i = base + t * 4 + j;
        vals[j] = (i < N) ? cnt[i] : 0;
        local += vals[j];
    }
    sdata[t] = local; __syncthreads();
    for (int o = 1; o < 256; o <<= 1) {
        int y = (t >= o) ? sdata[t - o] : 0;
        __syncthreads();
        sdata[t] += y;
        __syncthreads();
    }
    int run = sdata[t] - local + partial[b];
#pragma unroll
    for (int j = 0; j < 4; ++j) {
        int i = base + t * 4 + j;
        if (i < N) { off[i] = run; cnt[i] = run; }   // cnt becomes cursor
        run += vals[j];
    }
    if (b == 0 && t == 0) off[N] = E;
}

__global__ void fill_csr_kernel(const int* __restrict__ src, const int* __restrict__ dst,
                                int* __restrict__ cursor, int* __restrict__ csr, int E) {
    int e = blockIdx.x * blockDim.x + threadIdx.x;
    if (e < E) {
        int d = dst[e];
        int p = atomicAdd(&cursor[d], 1);
        csr[p] = src[e];
    }
}

// ===== gather-mean D=256 from fp8: 4 rows per load (16 lanes each, 16B/lane) =====
__global__ void gather_mean256_kernel(const unsigned int* __restrict__ feat8, const int* __restrict__ off,
                                      const int* __restrict__ csr, unsigned short* __restrict__ agg, int N) {
    int wid  = (int)((blockIdx.x * (long long)blockDim.x + threadIdx.x) >> 6);
    int lane = threadIdx.x & 63;
    if (wid >= N) return;
    int start = off[wid], end = off[wid + 1];
    const int g   = lane >> 4;           // 0..3: which row of the quad
    const int cl  = lane & 15;           // 16 fp8 cols per lane -> 256
    float a[16] = {};
    int e = start;
    for (; e + 7 < end; e += 8) {        // 2 quads in flight
        int s0 = csr[e + g], s1 = csr[e + 4 + g];
        uint4v v0 = *(const uint4v*)(feat8 + (long long)s0 * 64 + cl * 4);
        uint4v v1 = *(const uint4v*)(feat8 + (long long)s1 * 64 + cl * 4);
#pragma unroll
        for (int d = 0; d < 4; ++d) {
            f32x2 p0 = __builtin_amdgcn_cvt_pk_f32_fp8((int)v0[d], false);
            f32x2 p1 = __builtin_amdgcn_cvt_pk_f32_fp8((int)v0[d], true);
            f32x2 q0 = __builtin_amdgcn_cvt_pk_f32_fp8((int)v1[d], false);
            f32x2 q1 = __builtin_amdgcn_cvt_pk_f32_fp8((int)v1[d], true);
            a[d * 4 + 0] += p0[0] + q0[0];
            a[d * 4 + 1] += p0[1] + q0[1];
            a[d * 4 + 2] += p1[0] + q1[0];
            a[d * 4 + 3] += p1[1] + q1[1];
        }
    }
    for (; e < end; e += 4) {
        int idx = e + g;
        if (idx < end) {
            int s = csr[idx];
            uint4v v = *(const uint4v*)(feat8 + (long long)s * 64 + cl * 4);
#pragma unroll
            for (int d = 0; d < 4; ++d) {
                f32x2 p0 = __builtin_amdgcn_cvt_pk_f32_fp8((int)v[d], false);
                f32x2 p1 = __builtin_amdgcn_cvt_pk_f32_fp8((int)v[d], true);
                a[d * 4 + 0] += p0[0];
                a[d * 4 + 1] += p0[1];
                a[d * 4 + 2] += p1[0];
                a[d * 4 + 3] += p1[1];
            }
        }
    }
#pragma unroll
    for (int j = 0; j < 16; ++j) {
        a[j] += __shfl_xor(a[j], 16);
        a[j] += __shfl_xor(a[j], 32);
    }
    if (g == 0) {
        float inv = 1.0f / (float)max(end - start, 1);
        ushort8v o0, o1;
#pragma unroll
        for (int j = 0; j < 8; ++j) { o0[j] = f2bf(a[j] * inv); o1[j] = f2bf(a[8 + j] * inv); }
        unsigned short* dstp = agg + (long long)wid * 256 + cl * 16;
        *(ushort8v*)dstp       = o0;   // plain store: agg read by gemm1 next
        *(ushort8v*)(dstp + 8) = o1;
    }
}

// ================= GEMM 1: h1 = relu(feat@Ws1 + agg@Wn1 + b1) =================
// tile 128 rows x 256 cols, 8 waves (2 x 4), BK=32, two A-passes. LDS-staged A and B.
__global__ __launch_bounds__(512)
void gemm1_kernel(const unsigned short* __restrict__ A,  const unsigned short* __restrict__ WT,
                  const unsigned short* __restrict__ A2, const unsigned short* __restrict__ WT2,
                  const float* __restrict__ bias, unsigned short* __restrict__ C, int M)
{
    const int K = 256;
    __shared__ __align__(16) char lds[2][24576];   // A: [0,8192)  B: [8192,24576)

    const int tid = threadIdx.x;
    const int wid = tid >> 6, lane = tid & 63;
    const int l15 = lane & 15, lg = lane >> 4;
    const int wr = wid >> 2, wc = wid & 3;
    const int row0 = blockIdx.x * 128;

    long long asrc; int adst;
    {
        int c = tid, r = c >> 2, s = c & 3;
        int kc = s ^ ((r >> 1) & 3);
        asrc = (long long)min(row0 + r, M - 1) * K + kc * 8;
        adst = c * 16;
    }
    long long bsrc[2]; int bdst[2];
#pragma unroll
    for (int i = 0; i < 2; ++i) {
        int c = wid * 128 + i * 64 + lane, r = c >> 2, s = c & 3;
        int kc = s ^ ((r >> 1) & 3);
        bsrc[i] = (long long)r * K + kc * 8;
        bdst[i] = 8192 + c * 16;
    }

    const int slot = (lg ^ ((l15 >> 1) & 3)) * 16;
    int aoff[4], boff[4];
#pragma unroll
    for (int m = 0; m < 4; ++m) aoff[m] = (wr * 64 + m * 16 + l15) * 64 + slot;
#pragma unroll
    for (int n = 0; n < 4; ++n) boff[n] = 8192 + (wc * 64 + n * 16 + l15) * 64 + slot;

    f32x4 acc[4][4] = {};

    auto stage = [&](int buf, int t) {
        const unsigned short* Ap = (t >= 8) ? A2 : A;
        const unsigned short* Wp = (t >= 8) ? WT2 : WT;
        int k0 = (t & 7) * 32;
        gload16(Ap + asrc + k0, &lds[buf][adst]);
        gload16(Wp + bsrc[0] + k0, &lds[buf][bdst[0]]);
        gload16(Wp + bsrc[1] + k0, &lds[buf][bdst[1]]);
    };

    stage(0, 0);
    __syncthreads();

    for (int t = 0; t < 16; ++t) {
        const int cur = t & 1;
        if (t + 1 < 16) stage(cur ^ 1, t + 1);
        const char* L = lds[cur];
        bf16x8 af[4], bfr[4];
#pragma unroll
        for (int m = 0; m < 4; ++m) af[m]  = *(const bf16x8*)(L + aoff[m]);
#pragma unroll
        for (int n = 0; n < 4; ++n) bfr[n] = *(const bf16x8*)(L + boff[n]);
#pragma unroll
        for (int m = 0; m < 4; ++m)
#pragma unroll
            for (int n = 0; n < 4; ++n)
                acc[m][n] = __builtin_amdgcn_mfma_f32_16x16x32_bf16(af[m], bfr[n], acc[m][n], 0, 0, 0);
        __syncthreads();
    }

#pragma unroll
    for (int m = 0; m < 4; ++m) {
#pragma unroll
        for (int rr = 0; rr < 4; ++rr) {
            int grow = row0 + wr * 64 + m * 16 + lg * 4 + rr;
            if (grow >= M) continue;
#pragma unroll
            for (int n = 0; n < 4; ++n) {
                int gcol = wc * 64 + n * 16 + l15;
                float v = fmaxf(acc[m][n][rr] + bias[gcol], 0.f);
                C[(long long)grow * 256 + gcol] = f2bf(v);
            }
        }
    }
}

// ====== GEMM 23: [p2 | self2+b2] = h1 @ wcat^T  (single K=256 pass, split epilogue) ======
__global__ __launch_bounds__(512)
void gemm23_kernel(const unsigned short* __restrict__ A, const unsigned short* __restrict__ WT,
                   const float* __restrict__ b2,
                   unsigned short* __restrict__ p2, unsigned short* __restrict__ self2, int M)
{
    const int K = 256;
    __shared__ __align__(16) char lds[2][24576];   // A: [0,8192)  B: [8192,24576)

    const int tid = threadIdx.x;
    const int wid = tid >> 6, lane = tid & 63;
    const int l15 = lane & 15, lg = lane >> 4;
    const int wr = wid >> 2, wc = wid & 3;
    const int row0 = blockIdx.x * 128;

    long long asrc; int adst;
    {
        int c = tid, r = c >> 2, s = c & 3;
        int kc = s ^ ((r >> 1) & 3);
        asrc = (long long)min(row0 + r, M - 1) * K + kc * 8;
        adst = c * 16;
    }
    long long bsrc[2]; int bdst[2];
#pragma unroll
    for (int i = 0; i < 2; ++i) {
        int c = wid * 128 + i * 64 + lane, r = c >> 2, s = c & 3;
        int kc = s ^ ((r >> 1) & 3);
        bsrc[i] = (long long)r * K + kc * 8;
        bdst[i] = 8192 + c * 16;
    }

    const int slot = (lg ^ ((l15 >> 1) & 3)) * 16;
    int aoff[4], boff[4];
#pragma unroll
    for (int m = 0; m < 4; ++m) aoff[m] = (wr * 64 + m * 16 + l15) * 64 + slot;
#pragma unroll
    for (int n = 0; n < 4; ++n) boff[n] = 8192 + (wc * 64 + n * 16 + l15) * 64 + slot;

    f32x4 acc[4][4] = {};

    auto stage = [&](int buf, int t) {
        int k0 = t * 32;
        gload16(A  + asrc + k0, &lds[buf][adst]);
        gload16(WT + bsrc[0] + k0, &lds[buf][bdst[0]]);
        gload16(WT + bsrc[1] + k0, &lds[buf][bdst[1]]);
    };

    stage(0, 0);
    __syncthreads();

    for (int t = 0; t < 8; ++t) {
        const int cur = t & 1;
        if (t + 1 < 8) stage(cur ^ 1, t + 1);
        const char* L = lds[cur];
        bf16x8 af[4], bfr[4];
#pragma unroll
        for (int m = 0; m < 4; ++m) af[m]  = *(const bf16x8*)(L + aoff[m]);
#pragma unroll
        for (int n = 0; n < 4; ++n) bfr[n] = *(const bf16x8*)(L + boff[n]);
#pragma unroll
        for (int m = 0; m < 4; ++m)
#pragma unroll
            for (int n = 0; n < 4; ++n)
                acc[m][n] = __builtin_amdgcn_mfma_f32_16x16x32_bf16(af[m], bfr[n], acc[m][n], 0, 0, 0);
        __syncthreads();
    }

    // epilogue: cols 0-127 (wc 0/1) -> p2; cols 128-255 (wc 2/3) -> self2 (+b2)
    // plain stores: p2/self2 are read by gather_final next -> keep cached
    if (wc < 2) {
#pragma unroll
        for (int m = 0; m < 4; ++m)
#pragma unroll
            for (int rr = 0; rr < 4; ++rr) {
                int grow = row0 + wr * 64 + m * 16 + lg * 4 + rr;
                if (grow >= M) continue;
#pragma unroll
                for (int n = 0; n < 4; ++n) {
                    int col = wc * 64 + n * 16 + l15;
                    p2[(long long)grow * 128 + col] = f2bf(acc[m][n][rr]);
                }
            }
    } else {
        float bv[4];
#pragma unroll
        for (int n = 0; n < 4; ++n) bv[n] = b2[(wc - 2) * 64 + n * 16 + l15];
#pragma unroll
        for (int m = 0; m < 4; ++m)
#pragma unroll
            for (int rr = 0; rr < 4; ++rr) {
                int grow = row0 + wr * 64 + m * 16 + lg * 4 + rr;
                if (grow >= M) continue;
#pragma unroll
                for (int n = 0; n < 4; ++n) {
                    int col = (wc - 2) * 64 + n * 16 + l15;
                    self2[(long long)grow * 128 + col] = f2bf(acc[m][n][rr] + bv[n]);
                }
            }
    }
}

// ===== gather128 + final: out = normalize(relu(self2 + mean_nb(p2))) , one wave/node =====
__global__ void gather_final_kernel(const unsigned short* __restrict__ p2, const int* __restrict__ off,
                                    const int* __restrict__ csr, const unsigned short* __restrict__ self2,
                                    float* __restrict__ out, int N) {
    int wid  = (int)((blockIdx.x * (long long)blockDim.x + threadIdx.x) >> 6);
    int lane = threadIdx.x & 63;
    if (wid >= N) return;
    int start = off[wid], end = off[wid + 1];
    const int g  = lane >> 4;            // 0..3: which row of the quad
    const int c8 = (lane & 15) * 8;      // 8 cols per lane -> 128
    float a[8] = {};
    int e = start;
    for (; e + 7 < end; e += 8) {        // 2 quads in flight
        int s0 = csr[e + g], s1 = csr[e + 4 + g];
        ushort8v v0 = *(const ushort8v*)(p2 + (long long)s0 * 128 + c8);
        ushort8v v1 = *(const ushort8v*)(p2 + (long long)s1 * 128 + c8);
#pragma unroll
        for (int j = 0; j < 8; ++j) a[j] += bf2f(v0[j]) + bf2f(v1[j]);
    }
    for (; e < end; e += 4) {
        int idx = e + g;
        if (idx < end) {
            int s = csr[idx];
            ushort8v v = *(const ushort8v*)(p2 + (long long)s * 128 + c8);
#pragma unroll
            for (int j = 0; j < 8; ++j) a[j] += bf2f(v[j]);
        }
    }
#pragma unroll
    for (int j = 0; j < 8; ++j) {
        a[j] += __shfl_xor(a[j], 16);
        a[j] += __shfl_xor(a[j], 32);
    }
    float invd = 1.0f / (float)max(end - start, 1);
    ushort8v sv = *(const ushort8v*)(self2 + (long long)wid * 128 + c8);
    float v[8];
    float ss = 0.f;
#pragma unroll
    for (int j = 0; j < 8; ++j) {
        v[j] = fmaxf(bf2f(sv[j]) + a[j] * invd, 0.f);
        ss += v[j] * v[j];
    }
    ss += __shfl_xor(ss, 1);
    ss += __shfl_xor(ss, 2);
    ss += __shfl_xor(ss, 4);
    ss += __shfl_xor(ss, 8);
    float inv = 1.0f / fmaxf(sqrtf(ss), 1e-12f);
    if (g == 0) {
        f32x4 o0 = { v[0] * inv, v[1] * inv, v[2] * inv, v[3] * inv };
        f32x4 o1 = { v[4] * inv, v[5] * inv, v[6] * inv, v[7] * inv };
        float* dstp = out + (long long)wid * 128 + c8;
        __builtin_nontemporal_store(o0, (f32x4*)dstp);     // final output: never re-read
        __builtin_nontemporal_store(o1, (f32x4*)(dstp + 4));
    }
}

extern "C" void kernel_launch(void* const* d_in, const int* in_sizes, int n_in,
                              void* d_out, int out_size, void* d_ws, size_t ws_size,
                              hipStream_t stream) {
    const float* feat     = (const float*)d_in[0];
    const int*   src      = (const int*)  d_in[1];
    const int*   dst      = (const int*)  d_in[2];
    const float* w_self1  = (const float*)d_in[3];
    const float* w_neigh1 = (const float*)d_in[4];
    const float* b1       = (const float*)d_in[5];
    const float* w_self2  = (const float*)d_in[6];
    const float* w_neigh2 = (const float*)d_in[7];
    const float* b2       = (const float*)d_in[8];
    float* out = (float*)d_out;

    const int N = in_sizes[0] / DIN;    // 100000
    const int E = in_sizes[1];          // 800000

    char* ws = (char*)d_ws;
    auto a4k = [](size_t x) { return (x + 4095) & ~(size_t)4095; };
    size_t o = 0;
    int* cnt  = (int*)(ws + o); o += a4k((size_t)N * 4);
    int* off  = (int*)(ws + o); o += a4k((size_t)(N + 1) * 4);
    int* part = (int*)(ws + o); o += a4k(1024);
    int* csr  = (int*)(ws + o); o += a4k((size_t)E * 4);
    unsigned short* ws1t = (unsigned short*)(ws + o); o += a4k((size_t)DIN * DH * 2);
    unsigned short* wn1t = (unsigned short*)(ws + o); o += a4k((size_t)DIN * DH * 2);
    unsigned short* wcat = (unsigned short*)(ws + o); o += a4k((size_t)256 * 256 * 2);
    unsigned int*   feat8 = (unsigned int*)(ws + o); o += a4k((size_t)N * DIN);       // fp8 mirror
    unsigned short* featb = (unsigned short*)(ws + o); o += a4k((size_t)N * DIN * 2);  // reused: p2b
    unsigned short* aggb  = (unsigned short*)(ws + o); o += a4k((size_t)N * DIN * 2);  // reused: self2b
    unsigned short* h1b   = (unsigned short*)(ws + o); o += a4k((size_t)N * DH * 2);

    unsigned short* p2b    = featb;   // dead after gemm1
    unsigned short* self2b = aggb;    // dead after gemm1

    const int nblk = (N + 1023) / 1024;

    // ---- prep: cvt (bf16 + fp8, 64B/thread) + wtrans + count (cnt zeroed first) ----
    hipMemsetAsync(cnt, 0, (size_t)N * 4, stream);
    long long n16 = (long long)N * DIN / 16;
    const int bCvt = (int)((n16 + 255) / 256);      // 6250
    const int bWt  = 768;
    const int bCnt = (E + 255) / 256;               // 3125
    prep_kernel<<<bCvt + bWt + bCnt, 256, 0, stream>>>(
        feat, featb, feat8, n16, w_self1, w_neigh1, w_self2, w_neigh2,
        ws1t, wn1t, wcat, dst, cnt, E, bCvt, bWt);

    // ---- CSR scan + fill ----
    block_sums_kernel<<<nblk, 256, 0, stream>>>(cnt, part, N);
    scan_partials_kernel<<<1, 256, 0, stream>>>(part, nblk);
    scan_block_kernel<<<nblk, 256, 0, stream>>>(cnt, part, off, N, E);   // also inits cursor (cnt)
    fill_csr_kernel<<<(E + 255) / 256, 256, 0, stream>>>(src, dst, cnt, csr, E);

    const int mblk = (N + 127) / 128;   // 782

    // ---- layer 1: fp8 gather + bf16 MFMA GEMM ----
    gather_mean256_kernel<<<(N + 3) / 4, 256, 0, stream>>>(feat8, off, csr, aggb, N);
    gemm1_kernel<<<mblk, 512, 0, stream>>>(featb, ws1t, aggb, wn1t, b1, h1b, N);

    // ---- layer 2: both projections in one pass, then fused gather+norm ----
    gemm23_kernel<<<mblk, 512, 0, stream>>>(h1b, wcat, b2, p2b, self2b, N);
    gather_final_kernel<<<(N + 3) / 4, 256, 0, stream>>>(p2b, off, csr, self2b, out, N);
}

// Round 12
// 287.127 us; speedup vs baseline: 1.2132x; 1.0263x over previous
//
#include <hip/hip_runtime.h>

#define DIN 256
#define DH  256
#define DOUT 128

typedef __attribute__((ext_vector_type(8))) short bf16x8;
typedef __attribute__((ext_vector_type(4))) float f32x4;
typedef __attribute__((ext_vector_type(2))) float f32x2;
typedef __attribute__((ext_vector_type(4))) unsigned short ushort4v;
typedef __attribute__((ext_vector_type(8))) unsigned short ushort8v;
typedef __attribute__((ext_vector_type(4))) unsigned int uint4v;

static __device__ __forceinline__ unsigned short f2bf(float x) {
    unsigned u = __float_as_uint(x);
    u += 0x7fffu + ((u >> 16) & 1u);          // round-to-nearest-even
    return (unsigned short)(u >> 16);
}
static __device__ __forceinline__ float bf2f(unsigned short h) {
    return __uint_as_float(((unsigned)h) << 16);
}

static __device__ __forceinline__ void gload16(const unsigned short* g, void* l) {
    __builtin_amdgcn_global_load_lds(
        (const __attribute__((address_space(1))) unsigned int*)g,
        (__attribute__((address_space(3))) unsigned int*)l,
        16, 0, 0);
}

// ======== prep: feat->bf16 + fp8 (fully coalesced, 16B/lane) | wtrans | degree count ====
__global__ void prep_kernel(const float* __restrict__ feat, unsigned short* __restrict__ featb,
                            unsigned int* __restrict__ feat8, long long nc4,
                            const float* __restrict__ w_self1, const float* __restrict__ w_neigh1,
                            const float* __restrict__ w_self2, const float* __restrict__ w_neigh2,
                            unsigned short* __restrict__ ws1t, unsigned short* __restrict__ wn1t,
                            unsigned short* __restrict__ wcat,
                            const int* __restrict__ dst, int* __restrict__ cnt, int E,
                            int bCvt, int bWt) {
    int b = blockIdx.x;
    if (b < bCvt) {
        long long i = b * 256LL + threadIdx.x;     // f32x4 chunk index: lane i -> base+i*16B
        if (i >= nc4) return;
        f32x4 v = __builtin_nontemporal_load((const f32x4*)feat + i);
        ushort4v o;
        o[0] = f2bf(v[0]); o[1] = f2bf(v[1]); o[2] = f2bf(v[2]); o[3] = f2bf(v[3]);
        *((ushort4v*)featb + i) = o;               // plain store: cached for gemm1
        int u = __builtin_amdgcn_cvt_pk_fp8_f32(v[0], v[1], 0, 0);
        u     = __builtin_amdgcn_cvt_pk_fp8_f32(v[2], v[3], u, 1);
        feat8[i] = (unsigned)u;                    // plain store: must stay L2/L3-hot
    } else if (b < bCvt + bWt) {
        int idx = (b - bCvt) * 256 + threadIdx.x;
        if (idx < 65536) {                      // ws1t[n][k] = w_self1[k][n]
            int nn = idx >> 8, k = idx & 255;
            ws1t[idx] = f2bf(w_self1[k * 256 + nn]);
        } else if (idx < 131072) {              // wn1t
            int j = idx - 65536; int nn = j >> 8, k = j & 255;
            wn1t[j] = f2bf(w_neigh1[k * 256 + nn]);
        } else if (idx < 163840) {              // wcat rows 0..127 = wn2^T
            int j = idx - 131072; int nn = j >> 8, k = j & 255;
            wcat[j] = f2bf(w_neigh2[k * 128 + nn]);
        } else if (idx < 196608) {              // wcat rows 128..255 = ws2^T
            int j = idx - 163840; int nn = j >> 8, k = j & 255;
            wcat[32768 + j] = f2bf(w_self2[k * 128 + nn]);
        }
    } else {
        int e = (b - bCvt - bWt) * 256 + threadIdx.x;
        if (e < E) atomicAdd(&cnt[dst[e]], 1);
    }
}

// ================= CSR scan / fill =================
__global__ void block_sums_kernel(const int* __restrict__ cnt, int* __restrict__ partial, int N) {
    __shared__ int sdata[256];
    int t = threadIdx.x;
    int base = blockIdx.x * 1024;
    int s = 0;
#pragma unroll
    for (int j = 0; j < 4; ++j) {
        int i = base + t * 4 + j;
        if (i < N) s += cnt[i];
    }
    sdata[t] = s; __syncthreads();
    for (int o = 128; o; o >>= 1) {
        if (t < o) sdata[t] += sdata[t + o];
        __syncthreads();
    }
    if (t == 0) partial[blockIdx.x] = sdata[0];
}

__global__ void scan_partials_kernel(int* __restrict__ partial, int nb) {
    __shared__ int sdata[256];
    int t = threadIdx.x;
    int v = (t < nb) ? partial[t] : 0;
    sdata[t] = v; __syncthreads();
    for (int o = 1; o < 256; o <<= 1) {
        int y = (t >= o) ? sdata[t - o] : 0;
        __syncthreads();
        sdata[t] += y;
        __syncthreads();
    }
    if (t < nb) partial[t] = sdata[t] - v;
}

// writes offsets AND initializes the fill-cursor (same values)
__global__ void scan_block_kernel(int* __restrict__ cnt, const int* __restrict__ partial,
                                  int* __restrict__ off, int N, int E) {
    __shared__ int sdata[256];
    int b = blockIdx.x, t = threadIdx.x;
    int base = b * 1024;
    int vals[4]; int local = 0;
#pragma unroll
    for (int j = 0; j < 4; ++j) {
        int i = base + t * 4 + j;
        vals[j] = (i < N) ? cnt[i] : 0;
        local += vals[j];
    }
    sdata[t] = local; __syncthreads();
    for (int o = 1; o < 256; o <<= 1) {
        int y = (t >= o) ? sdata[t - o] : 0;
        __syncthreads();
        sdata[t] += y;
        __syncthreads();
    }
    int run = sdata[t] - local + partial[b];
#pragma unroll
    for (int j = 0; j < 4; ++j) {
        int i = base + t * 4 + j;
        if (i < N) { off[i] = run; cnt[i] = run; }   // cnt becomes cursor
        run += vals[j];
    }
    if (b == 0 && t == 0) off[N] = E;
}

__global__ void fill_csr_kernel(const int* __restrict__ src, const int* __restrict__ dst,
                                int* __restrict__ cursor, int* __restrict__ csr, int E) {
    int e = blockIdx.x * blockDim.x + threadIdx.x;
    if (e < E) {
        int d = dst[e];
        int p = atomicAdd(&cursor[d], 1);
        csr[p] = src[e];
    }
}

// ===== gather-mean D=256 from fp8: 4 rows per load (16 lanes each, 16B/lane) =====
__global__ void gather_mean256_kernel(const unsigned int* __restrict__ feat8, const int* __restrict__ off,
                                      const int* __restrict__ csr, unsigned short* __restrict__ agg, int N) {
    int wid  = (int)((blockIdx.x * (long long)blockDim.x + threadIdx.x) >> 6);
    int lane = threadIdx.x & 63;
    if (wid >= N) return;
    int start = off[wid], end = off[wid + 1];
    const int g   = lane >> 4;           // 0..3: which row of the quad
    const int cl  = lane & 15;           // 16 fp8 cols per lane -> 256
    float a[16] = {};
    int e = start;
    for (; e + 7 < end; e += 8) {        // 2 quads in flight
        int s0 = csr[e + g], s1 = csr[e + 4 + g];
        uint4v v0 = *(const uint4v*)(feat8 + (long long)s0 * 64 + cl * 4);
        uint4v v1 = *(const uint4v*)(feat8 + (long long)s1 * 64 + cl * 4);
#pragma unroll
        for (int d = 0; d < 4; ++d) {
            f32x2 p0 = __builtin_amdgcn_cvt_pk_f32_fp8((int)v0[d], false);
            f32x2 p1 = __builtin_amdgcn_cvt_pk_f32_fp8((int)v0[d], true);
            f32x2 q0 = __builtin_amdgcn_cvt_pk_f32_fp8((int)v1[d], false);
            f32x2 q1 = __builtin_amdgcn_cvt_pk_f32_fp8((int)v1[d], true);
            a[d * 4 + 0] += p0[0] + q0[0];
            a[d * 4 + 1] += p0[1] + q0[1];
            a[d * 4 + 2] += p1[0] + q1[0];
            a[d * 4 + 3] += p1[1] + q1[1];
        }
    }
    for (; e < end; e += 4) {
        int idx = e + g;
        if (idx < end) {
            int s = csr[idx];
            uint4v v = *(const uint4v*)(feat8 + (long long)s * 64 + cl * 4);
#pragma unroll
            for (int d = 0; d < 4; ++d) {
                f32x2 p0 = __builtin_amdgcn_cvt_pk_f32_fp8((int)v[d], false);
                f32x2 p1 = __builtin_amdgcn_cvt_pk_f32_fp8((int)v[d], true);
                a[d * 4 + 0] += p0[0];
                a[d * 4 + 1] += p0[1];
                a[d * 4 + 2] += p1[0];
                a[d * 4 + 3] += p1[1];
            }
        }
    }
#pragma unroll
    for (int j = 0; j < 16; ++j) {
        a[j] += __shfl_xor(a[j], 16);
        a[j] += __shfl_xor(a[j], 32);
    }
    if (g == 0) {
        float inv = 1.0f / (float)max(end - start, 1);
        ushort8v o0, o1;
#pragma unroll
        for (int j = 0; j < 8; ++j) { o0[j] = f2bf(a[j] * inv); o1[j] = f2bf(a[8 + j] * inv); }
        unsigned short* dstp = agg + (long long)wid * 256 + cl * 16;
        *(ushort8v*)dstp       = o0;   // plain store: agg read by gemm1 next
        *(ushort8v*)(dstp + 8) = o1;
    }
}

// ================= GEMM 1: h1 = relu(feat@Ws1 + agg@Wn1 + b1) =================
// tile 128 rows x 256 cols, 8 waves (2 x 4), BK=32, two A-passes. LDS-staged A and B.
__global__ __launch_bounds__(512)
void gemm1_kernel(const unsigned short* __restrict__ A,  const unsigned short* __restrict__ WT,
                  const unsigned short* __restrict__ A2, const unsigned short* __restrict__ WT2,
                  const float* __restrict__ bias, unsigned short* __restrict__ C, int M)
{
    const int K = 256;
    __shared__ __align__(16) char lds[2][24576];   // A: [0,8192)  B: [8192,24576)

    const int tid = threadIdx.x;
    const int wid = tid >> 6, lane = tid & 63;
    const int l15 = lane & 15, lg = lane >> 4;
    const int wr = wid >> 2, wc = wid & 3;
    const int row0 = blockIdx.x * 128;

    long long asrc; int adst;
    {
        int c = tid, r = c >> 2, s = c & 3;
        int kc = s ^ ((r >> 1) & 3);
        asrc = (long long)min(row0 + r, M - 1) * K + kc * 8;
        adst = c * 16;
    }
    long long bsrc[2]; int bdst[2];
#pragma unroll
    for (int i = 0; i < 2; ++i) {
        int c = wid * 128 + i * 64 + lane, r = c >> 2, s = c & 3;
        int kc = s ^ ((r >> 1) & 3);
        bsrc[i] = (long long)r * K + kc * 8;
        bdst[i] = 8192 + c * 16;
    }

    const int slot = (lg ^ ((l15 >> 1) & 3)) * 16;
    int aoff[4], boff[4];
#pragma unroll
    for (int m = 0; m < 4; ++m) aoff[m] = (wr * 64 + m * 16 + l15) * 64 + slot;
#pragma unroll
    for (int n = 0; n < 4; ++n) boff[n] = 8192 + (wc * 64 + n * 16 + l15) * 64 + slot;

    f32x4 acc[4][4] = {};

    auto stage = [&](int buf, int t) {
        const unsigned short* Ap = (t >= 8) ? A2 : A;
        const unsigned short* Wp = (t >= 8) ? WT2 : WT;
        int k0 = (t & 7) * 32;
        gload16(Ap + asrc + k0, &lds[buf][adst]);
        gload16(Wp + bsrc[0] + k0, &lds[buf][bdst[0]]);
        gload16(Wp + bsrc[1] + k0, &lds[buf][bdst[1]]);
    };

    stage(0, 0);
    __syncthreads();

    for (int t = 0; t < 16; ++t) {
        const int cur = t & 1;
        if (t + 1 < 16) stage(cur ^ 1, t + 1);
        const char* L = lds[cur];
        bf16x8 af[4], bfr[4];
#pragma unroll
        for (int m = 0; m < 4; ++m) af[m]  = *(const bf16x8*)(L + aoff[m]);
#pragma unroll
        for (int n = 0; n < 4; ++n) bfr[n] = *(const bf16x8*)(L + boff[n]);
#pragma unroll
        for (int m = 0; m < 4; ++m)
#pragma unroll
            for (int n = 0; n < 4; ++n)
                acc[m][n] = __builtin_amdgcn_mfma_f32_16x16x32_bf16(af[m], bfr[n], acc[m][n], 0, 0, 0);
        __syncthreads();
    }

#pragma unroll
    for (int m = 0; m < 4; ++m) {
#pragma unroll
        for (int rr = 0; rr < 4; ++rr) {
            int grow = row0 + wr * 64 + m * 16 + lg * 4 + rr;
            if (grow >= M) continue;
#pragma unroll
            for (int n = 0; n < 4; ++n) {
                int gcol = wc * 64 + n * 16 + l15;
                float v = fmaxf(acc[m][n][rr] + bias[gcol], 0.f);
                C[(long long)grow * 256 + gcol] = f2bf(v);
            }
        }
    }
}

// ====== GEMM 23: [p2 | self2+b2] = h1 @ wcat^T  (single K=256 pass, split epilogue) ======
__global__ __launch_bounds__(512)
void gemm23_kernel(const unsigned short* __restrict__ A, const unsigned short* __restrict__ WT,
                   const float* __restrict__ b2,
                   unsigned short* __restrict__ p2, unsigned short* __restrict__ self2, int M)
{
    const int K = 256;
    __shared__ __align__(16) char lds[2][24576];   // A: [0,8192)  B: [8192,24576)

    const int tid = threadIdx.x;
    const int wid = tid >> 6, lane = tid & 63;
    const int l15 = lane & 15, lg = lane >> 4;
    const int wr = wid >> 2, wc = wid & 3;
    const int row0 = blockIdx.x * 128;

    long long asrc; int adst;
    {
        int c = tid, r = c >> 2, s = c & 3;
        int kc = s ^ ((r >> 1) & 3);
        asrc = (long long)min(row0 + r, M - 1) * K + kc * 8;
        adst = c * 16;
    }
    long long bsrc[2]; int bdst[2];
#pragma unroll
    for (int i = 0; i < 2; ++i) {
        int c = wid * 128 + i * 64 + lane, r = c >> 2, s = c & 3;
        int kc = s ^ ((r >> 1) & 3);
        bsrc[i] = (long long)r * K + kc * 8;
        bdst[i] = 8192 + c * 16;
    }

    const int slot = (lg ^ ((l15 >> 1) & 3)) * 16;
    int aoff[4], boff[4];
#pragma unroll
    for (int m = 0; m < 4; ++m) aoff[m] = (wr * 64 + m * 16 + l15) * 64 + slot;
#pragma unroll
    for (int n = 0; n < 4; ++n) boff[n] = 8192 + (wc * 64 + n * 16 + l15) * 64 + slot;

    f32x4 acc[4][4] = {};

    auto stage = [&](int buf, int t) {
        int k0 = t * 32;
        gload16(A  + asrc + k0, &lds[buf][adst]);
        gload16(WT + bsrc[0] + k0, &lds[buf][bdst[0]]);
        gload16(WT + bsrc[1] + k0, &lds[buf][bdst[1]]);
    };

    stage(0, 0);
    __syncthreads();

    for (int t = 0; t < 8; ++t) {
        const int cur = t & 1;
        if (t + 1 < 8) stage(cur ^ 1, t + 1);
        const char* L = lds[cur];
        bf16x8 af[4], bfr[4];
#pragma unroll
        for (int m = 0; m < 4; ++m) af[m]  = *(const bf16x8*)(L + aoff[m]);
#pragma unroll
        for (int n = 0; n < 4; ++n) bfr[n] = *(const bf16x8*)(L + boff[n]);
#pragma unroll
        for (int m = 0; m < 4; ++m)
#pragma unroll
            for (int n = 0; n < 4; ++n)
                acc[m][n] = __builtin_amdgcn_mfma_f32_16x16x32_bf16(af[m], bfr[n], acc[m][n], 0, 0, 0);
        __syncthreads();
    }

    // epilogue: cols 0-127 (wc 0/1) -> p2; cols 128-255 (wc 2/3) -> self2 (+b2)
    // plain stores: p2/self2 are read by gather_final next -> keep cached
    if (wc < 2) {
#pragma unroll
        for (int m = 0; m < 4; ++m)
#pragma unroll
            for (int rr = 0; rr < 4; ++rr) {
                int grow = row0 + wr * 64 + m * 16 + lg * 4 + rr;
                if (grow >= M) continue;
#pragma unroll
                for (int n = 0; n < 4; ++n) {
                    int col = wc * 64 + n * 16 + l15;
                    p2[(long long)grow * 128 + col] = f2bf(acc[m][n][rr]);
                }
            }
    } else {
        float bv[4];
#pragma unroll
        for (int n = 0; n < 4; ++n) bv[n] = b2[(wc - 2) * 64 + n * 16 + l15];
#pragma unroll
        for (int m = 0; m < 4; ++m)
#pragma unroll
            for (int rr = 0; rr < 4; ++rr) {
                int grow = row0 + wr * 64 + m * 16 + lg * 4 + rr;
                if (grow >= M) continue;
#pragma unroll
                for (int n = 0; n < 4; ++n) {
                    int col = (wc - 2) * 64 + n * 16 + l15;
                    self2[(long long)grow * 128 + col] = f2bf(acc[m][n][rr] + bv[n]);
                }
            }
    }
}

// ===== gather128 + final: out = normalize(relu(self2 + mean_nb(p2))) , one wave/node =====
__global__ void gather_final_kernel(const unsigned short* __restrict__ p2, const int* __restrict__ off,
                                    const int* __restrict__ csr, const unsigned short* __restrict__ self2,
                                    float* __restrict__ out, int N) {
    int wid  = (int)((blockIdx.x * (long long)blockDim.x + threadIdx.x) >> 6);
    int lane = threadIdx.x & 63;
    if (wid >= N) return;
    int start = off[wid], end = off[wid + 1];
    const int g  = lane >> 4;            // 0..3: which row of the quad
    const int c8 = (lane & 15) * 8;      // 8 cols per lane -> 128
    float a[8] = {};
    int e = start;
    for (; e + 7 < end; e += 8) {        // 2 quads in flight
        int s0 = csr[e + g], s1 = csr[e + 4 + g];
        ushort8v v0 = *(const ushort8v*)(p2 + (long long)s0 * 128 + c8);
        ushort8v v1 = *(const ushort8v*)(p2 + (long long)s1 * 128 + c8);
#pragma unroll
        for (int j = 0; j < 8; ++j) a[j] += bf2f(v0[j]) + bf2f(v1[j]);
    }
    for (; e < end; e += 4) {
        int idx = e + g;
        if (idx < end) {
            int s = csr[idx];
            ushort8v v = *(const ushort8v*)(p2 + (long long)s * 128 + c8);
#pragma unroll
            for (int j = 0; j < 8; ++j) a[j] += bf2f(v[j]);
        }
    }
#pragma unroll
    for (int j = 0; j < 8; ++j) {
        a[j] += __shfl_xor(a[j], 16);
        a[j] += __shfl_xor(a[j], 32);
    }
    float invd = 1.0f / (float)max(end - start, 1);
    ushort8v sv = *(const ushort8v*)(self2 + (long long)wid * 128 + c8);
    float v[8];
    float ss = 0.f;
#pragma unroll
    for (int j = 0; j < 8; ++j) {
        v[j] = fmaxf(bf2f(sv[j]) + a[j] * invd, 0.f);
        ss += v[j] * v[j];
    }
    ss += __shfl_xor(ss, 1);
    ss += __shfl_xor(ss, 2);
    ss += __shfl_xor(ss, 4);
    ss += __shfl_xor(ss, 8);
    float inv = 1.0f / fmaxf(sqrtf(ss), 1e-12f);
    if (g == 0) {
        f32x4 o0 = { v[0] * inv, v[1] * inv, v[2] * inv, v[3] * inv };
        f32x4 o1 = { v[4] * inv, v[5] * inv, v[6] * inv, v[7] * inv };
        float* dstp = out + (long long)wid * 128 + c8;
        __builtin_nontemporal_store(o0, (f32x4*)dstp);     // final output: never re-read
        __builtin_nontemporal_store(o1, (f32x4*)(dstp + 4));
    }
}

extern "C" void kernel_launch(void* const* d_in, const int* in_sizes, int n_in,
                              void* d_out, int out_size, void* d_ws, size_t ws_size,
                              hipStream_t stream) {
    const float* feat     = (const float*)d_in[0];
    const int*   src      = (const int*)  d_in[1];
    const int*   dst      = (const int*)  d_in[2];
    const float* w_self1  = (const float*)d_in[3];
    const float* w_neigh1 = (const float*)d_in[4];
    const float* b1       = (const float*)d_in[5];
    const float* w_self2  = (const float*)d_in[6];
    const float* w_neigh2 = (const float*)d_in[7];
    const float* b2       = (const float*)d_in[8];
    float* out = (float*)d_out;

    const int N = in_sizes[0] / DIN;    // 100000
    const int E = in_sizes[1];          // 800000

    char* ws = (char*)d_ws;
    auto a4k = [](size_t x) { return (x + 4095) & ~(size_t)4095; };
    size_t o = 0;
    int* cnt  = (int*)(ws + o); o += a4k((size_t)N * 4);
    int* off  = (int*)(ws + o); o += a4k((size_t)(N + 1) * 4);
    int* part = (int*)(ws + o); o += a4k(1024);
    int* csr  = (int*)(ws + o); o += a4k((size_t)E * 4);
    unsigned short* ws1t = (unsigned short*)(ws + o); o += a4k((size_t)DIN * DH * 2);
    unsigned short* wn1t = (unsigned short*)(ws + o); o += a4k((size_t)DIN * DH * 2);
    unsigned short* wcat = (unsigned short*)(ws + o); o += a4k((size_t)256 * 256 * 2);
    unsigned int*   feat8 = (unsigned int*)(ws + o); o += a4k((size_t)N * DIN);       // fp8 mirror
    unsigned short* featb = (unsigned short*)(ws + o); o += a4k((size_t)N * DIN * 2);  // reused: p2b
    unsigned short* aggb  = (unsigned short*)(ws + o); o += a4k((size_t)N * DIN * 2);  // reused: self2b
    unsigned short* h1b   = (unsigned short*)(ws + o); o += a4k((size_t)N * DH * 2);

    unsigned short* p2b    = featb;   // dead after gemm1
    unsigned short* self2b = aggb;    // dead after gemm1

    const int nblk = (N + 1023) / 1024;

    // ---- prep: cvt (bf16 + fp8, coalesced 16B/lane) + wtrans + count (cnt zeroed first) ----
    hipMemsetAsync(cnt, 0, (size_t)N * 4, stream);
    long long nc4 = (long long)N * DIN / 4;         // f32x4 chunks: 6.4e6
    const int bCvt = (int)((nc4 + 255) / 256);      // 25000
    const int bWt  = 768;
    const int bCnt = (E + 255) / 256;               // 3125
    prep_kernel<<<bCvt + bWt + bCnt, 256, 0, stream>>>(
        feat, featb, feat8, nc4, w_self1, w_neigh1, w_self2, w_neigh2,
        ws1t, wn1t, wcat, dst, cnt, E, bCvt, bWt);

    // ---- CSR scan + fill ----
    block_sums_kernel<<<nblk, 256, 0, stream>>>(cnt, part, N);
    scan_partials_kernel<<<1, 256, 0, stream>>>(part, nblk);
    scan_block_kernel<<<nblk, 256, 0, stream>>>(cnt, part, off, N, E);   // also inits cursor (cnt)
    fill_csr_kernel<<<(E + 255) / 256, 256, 0, stream>>>(src, dst, cnt, csr, E);

    const int mblk = (N + 127) / 128;   // 782

    // ---- layer 1: fp8 gather + bf16 MFMA GEMM ----
    gather_mean256_kernel<<<(N + 3) / 4, 256, 0, stream>>>(feat8, off, csr, aggb, N);
    gemm1_kernel<<<mblk, 512, 0, stream>>>(featb, ws1t, aggb, wn1t, b1, h1b, N);

    // ---- layer 2: both projections in one pass, then fused gather+norm ----
    gemm23_kernel<<<mblk, 512, 0, stream>>>(h1b, wcat, b2, p2b, self2b, N);
    gather_final_kernel<<<(N + 3) / 4, 256, 0, stream>>>(p2b, off, csr, self2b, out, N);
}

// Round 13
// 282.494 us; speedup vs baseline: 1.2331x; 1.0164x over previous
//
#include <hip/hip_runtime.h>

#define DIN 256
#define DH  256
#define DOUT 128

typedef __attribute__((ext_vector_type(8))) short bf16x8;
typedef __attribute__((ext_vector_type(4))) float f32x4;
typedef __attribute__((ext_vector_type(2))) float f32x2;
typedef __attribute__((ext_vector_type(4))) unsigned short ushort4v;
typedef __attribute__((ext_vector_type(8))) unsigned short ushort8v;
typedef __attribute__((ext_vector_type(4))) unsigned int uint4v;

static __device__ __forceinline__ unsigned short f2bf(float x) {
    unsigned u = __float_as_uint(x);
    u += 0x7fffu + ((u >> 16) & 1u);          // round-to-nearest-even
    return (unsigned short)(u >> 16);
}
static __device__ __forceinline__ float bf2f(unsigned short h) {
    return __uint_as_float(((unsigned)h) << 16);
}

static __device__ __forceinline__ void gload16(const unsigned short* g, void* l) {
    __builtin_amdgcn_global_load_lds(
        (const __attribute__((address_space(1))) unsigned int*)g,
        (__attribute__((address_space(3))) unsigned int*)l,
        16, 0, 0);
}

// ==== prep: degree count FIRST (latency hides under cvt) | wtrans | feat->bf16+fp8 ====
__global__ void prep_kernel(const float* __restrict__ feat, unsigned short* __restrict__ featb,
                            unsigned int* __restrict__ feat8, long long ncHalf,
                            const float* __restrict__ w_self1, const float* __restrict__ w_neigh1,
                            const float* __restrict__ w_self2, const float* __restrict__ w_neigh2,
                            unsigned short* __restrict__ ws1t, unsigned short* __restrict__ wn1t,
                            unsigned short* __restrict__ wcat,
                            const int* __restrict__ dst, int* __restrict__ cnt, int E,
                            int bCnt, int bWt) {
    int b = blockIdx.x;
    if (b < bCnt) {
        // ---- degree count: dispatched FIRST so the atomic latency overlaps the cvt stream
        int e = b * 256 + threadIdx.x;
        if (e < E) atomicAdd(&cnt[dst[e]], 1);
    } else if (b < bCnt + bWt) {
        int idx = (b - bCnt) * 256 + threadIdx.x;
        if (idx < 65536) {                      // ws1t[n][k] = w_self1[k][n]
            int nn = idx >> 8, k = idx & 255;
            ws1t[idx] = f2bf(w_self1[k * 256 + nn]);
        } else if (idx < 131072) {              // wn1t
            int j = idx - 65536; int nn = j >> 8, k = j & 255;
            wn1t[j] = f2bf(w_neigh1[k * 256 + nn]);
        } else if (idx < 163840) {              // wcat rows 0..127 = wn2^T
            int j = idx - 131072; int nn = j >> 8, k = j & 255;
            wcat[j] = f2bf(w_neigh2[k * 128 + nn]);
        } else if (idx < 196608) {              // wcat rows 128..255 = ws2^T
            int j = idx - 163840; int nn = j >> 8, k = j & 255;
            wcat[32768 + j] = f2bf(w_self2[k * 128 + nn]);
        }
    } else {
        // ---- cvt: 2 independent coalesced chunks per thread (MLP=2)
        long long i = (b - bCnt - bWt) * 256LL + threadIdx.x;
        if (i >= ncHalf) return;
        long long i2 = i + ncHalf;
        f32x4 v0 = __builtin_nontemporal_load((const f32x4*)feat + i);
        f32x4 v1 = __builtin_nontemporal_load((const f32x4*)feat + i2);
        ushort4v o0, o1;
        o0[0] = f2bf(v0[0]); o0[1] = f2bf(v0[1]); o0[2] = f2bf(v0[2]); o0[3] = f2bf(v0[3]);
        o1[0] = f2bf(v1[0]); o1[1] = f2bf(v1[1]); o1[2] = f2bf(v1[2]); o1[3] = f2bf(v1[3]);
        *((ushort4v*)featb + i)  = o0;          // plain: cached for gemm1
        *((ushort4v*)featb + i2) = o1;
        int u0 = __builtin_amdgcn_cvt_pk_fp8_f32(v0[0], v0[1], 0, 0);
        u0     = __builtin_amdgcn_cvt_pk_fp8_f32(v0[2], v0[3], u0, 1);
        int u1 = __builtin_amdgcn_cvt_pk_fp8_f32(v1[0], v1[1], 0, 0);
        u1     = __builtin_amdgcn_cvt_pk_fp8_f32(v1[2], v1[3], u1, 1);
        feat8[i]  = (unsigned)u0;               // plain: must stay L2/L3-hot for gather
        feat8[i2] = (unsigned)u1;
    }
}

// ================= CSR scan / fill =================
__global__ void block_sums_kernel(const int* __restrict__ cnt, int* __restrict__ partial, int N) {
    __shared__ int sdata[256];
    int t = threadIdx.x;
    int base = blockIdx.x * 1024;
    int s = 0;
#pragma unroll
    for (int j = 0; j < 4; ++j) {
        int i = base + t * 4 + j;
        if (i < N) s += cnt[i];
    }
    sdata[t] = s; __syncthreads();
    for (int o = 128; o; o >>= 1) {
        if (t < o) sdata[t] += sdata[t + o];
        __syncthreads();
    }
    if (t == 0) partial[blockIdx.x] = sdata[0];
}

// fused: scans the (<=256) partials locally, then writes offsets AND inits cursor
__global__ void scan_block_kernel(int* __restrict__ cnt, const int* __restrict__ partial,
                                  int* __restrict__ off, int N, int E, int nb) {
    __shared__ int sdata[256];
    __shared__ int pbase;
    int b = blockIdx.x, t = threadIdx.x;

    // local inclusive scan of partials
    int pv = (t < nb) ? partial[t] : 0;
    sdata[t] = pv; __syncthreads();
    for (int o = 1; o < 256; o <<= 1) {
        int y = (t >= o) ? sdata[t - o] : 0;
        __syncthreads();
        sdata[t] += y;
        __syncthreads();
    }
    if (t == 0) pbase = (b == 0) ? 0 : sdata[b - 1];
    __syncthreads();
    int base0 = pbase;
    __syncthreads();   // sdata reuse below

    int base = b * 1024;
    int vals[4]; int local = 0;
#pragma unroll
    for (int j = 0; j < 4; ++j) {
        int i = base + t * 4 + j;
        vals[j] = (i < N) ? cnt[i] : 0;
        local += vals[j];
    }
    sdata[t] = local; __syncthreads();
    for (int o = 1; o < 256; o <<= 1) {
        int y = (t >= o) ? sdata[t - o] : 0;
        __syncthreads();
        sdata[t] += y;
        __syncthreads();
    }
    int run = sdata[t] - local + base0;
#pragma unroll
    for (int j = 0; j < 4; ++j) {
        int i = base + t * 4 + j;
        if (i < N) { off[i] = run; cnt[i] = run; }   // cnt becomes cursor
        run += vals[j];
    }
    if (b == 0 && t == 0) off[N] = E;
}

__global__ void fill_csr_kernel(const int* __restrict__ src, const int* __restrict__ dst,
                                int* __restrict__ cursor, int* __restrict__ csr, int E) {
    int e = blockIdx.x * blockDim.x + threadIdx.x;
    if (e < E) {
        int d = dst[e];
        int p = atomicAdd(&cursor[d], 1);
        csr[p] = src[e];
    }
}

// ===== gather-mean D=256 from fp8: 4 rows per load (16 lanes each, 16B/lane) =====
__global__ void gather_mean256_kernel(const unsigned int* __restrict__ feat8, const int* __restrict__ off,
                                      const int* __restrict__ csr, unsigned short* __restrict__ agg, int N) {
    int wid  = (int)((blockIdx.x * (long long)blockDim.x + threadIdx.x) >> 6);
    int lane = threadIdx.x & 63;
    if (wid >= N) return;
    int start = off[wid], end = off[wid + 1];
    const int g   = lane >> 4;           // 0..3: which row of the quad
    const int cl  = lane & 15;           // 16 fp8 cols per lane -> 256
    float a[16] = {};
    int e = start;
    for (; e + 7 < end; e += 8) {        // 2 quads in flight
        int s0 = csr[e + g], s1 = csr[e + 4 + g];
        uint4v v0 = *(const uint4v*)(feat8 + (long long)s0 * 64 + cl * 4);
        uint4v v1 = *(const uint4v*)(feat8 + (long long)s1 * 64 + cl * 4);
#pragma unroll
        for (int d = 0; d < 4; ++d) {
            f32x2 p0 = __builtin_amdgcn_cvt_pk_f32_fp8((int)v0[d], false);
            f32x2 p1 = __builtin_amdgcn_cvt_pk_f32_fp8((int)v0[d], true);
            f32x2 q0 = __builtin_amdgcn_cvt_pk_f32_fp8((int)v1[d], false);
            f32x2 q1 = __builtin_amdgcn_cvt_pk_f32_fp8((int)v1[d], true);
            a[d * 4 + 0] += p0[0] + q0[0];
            a[d * 4 + 1] += p0[1] + q0[1];
            a[d * 4 + 2] += p1[0] + q1[0];
            a[d * 4 + 3] += p1[1] + q1[1];
        }
    }
    for (; e < end; e += 4) {
        int idx = e + g;
        if (idx < end) {
            int s = csr[idx];
            uint4v v = *(const uint4v*)(feat8 + (long long)s * 64 + cl * 4);
#pragma unroll
            for (int d = 0; d < 4; ++d) {
                f32x2 p0 = __builtin_amdgcn_cvt_pk_f32_fp8((int)v[d], false);
                f32x2 p1 = __builtin_amdgcn_cvt_pk_f32_fp8((int)v[d], true);
                a[d * 4 + 0] += p0[0];
                a[d * 4 + 1] += p0[1];
                a[d * 4 + 2] += p1[0];
                a[d * 4 + 3] += p1[1];
            }
        }
    }
#pragma unroll
    for (int j = 0; j < 16; ++j) {
        a[j] += __shfl_xor(a[j], 16);
        a[j] += __shfl_xor(a[j], 32);
    }
    if (g == 0) {
        float inv = 1.0f / (float)max(end - start, 1);
        ushort8v o0, o1;
#pragma unroll
        for (int j = 0; j < 8; ++j) { o0[j] = f2bf(a[j] * inv); o1[j] = f2bf(a[8 + j] * inv); }
        unsigned short* dstp = agg + (long long)wid * 256 + cl * 16;
        *(ushort8v*)dstp       = o0;   // plain store: agg read by gemm1 next
        *(ushort8v*)(dstp + 8) = o1;
    }
}

// ================= GEMM 1: h1 = relu(feat@Ws1 + agg@Wn1 + b1) =================
__global__ __launch_bounds__(512)
void gemm1_kernel(const unsigned short* __restrict__ A,  const unsigned short* __restrict__ WT,
                  const unsigned short* __restrict__ A2, const unsigned short* __restrict__ WT2,
                  const float* __restrict__ bias, unsigned short* __restrict__ C, int M)
{
    const int K = 256;
    __shared__ __align__(16) char lds[2][24576];   // A: [0,8192)  B: [8192,24576)

    const int tid = threadIdx.x;
    const int wid = tid >> 6, lane = tid & 63;
    const int l15 = lane & 15, lg = lane >> 4;
    const int wr = wid >> 2, wc = wid & 3;
    const int row0 = blockIdx.x * 128;

    long long asrc; int adst;
    {
        int c = tid, r = c >> 2, s = c & 3;
        int kc = s ^ ((r >> 1) & 3);
        asrc = (long long)min(row0 + r, M - 1) * K + kc * 8;
        adst = c * 16;
    }
    long long bsrc[2]; int bdst[2];
#pragma unroll
    for (int i = 0; i < 2; ++i) {
        int c = wid * 128 + i * 64 + lane, r = c >> 2, s = c & 3;
        int kc = s ^ ((r >> 1) & 3);
        bsrc[i] = (long long)r * K + kc * 8;
        bdst[i] = 8192 + c * 16;
    }

    const int slot = (lg ^ ((l15 >> 1) & 3)) * 16;
    int aoff[4], boff[4];
#pragma unroll
    for (int m = 0; m < 4; ++m) aoff[m] = (wr * 64 + m * 16 + l15) * 64 + slot;
#pragma unroll
    for (int n = 0; n < 4; ++n) boff[n] = 8192 + (wc * 64 + n * 16 + l15) * 64 + slot;

    f32x4 acc[4][4] = {};

    auto stage = [&](int buf, int t) {
        const unsigned short* Ap = (t >= 8) ? A2 : A;
        const unsigned short* Wp = (t >= 8) ? WT2 : WT;
        int k0 = (t & 7) * 32;
        gload16(Ap + asrc + k0, &lds[buf][adst]);
        gload16(Wp + bsrc[0] + k0, &lds[buf][bdst[0]]);
        gload16(Wp + bsrc[1] + k0, &lds[buf][bdst[1]]);
    };

    stage(0, 0);
    __syncthreads();

    for (int t = 0; t < 16; ++t) {
        const int cur = t & 1;
        if (t + 1 < 16) stage(cur ^ 1, t + 1);
        const char* L = lds[cur];
        bf16x8 af[4], bfr[4];
#pragma unroll
        for (int m = 0; m < 4; ++m) af[m]  = *(const bf16x8*)(L + aoff[m]);
#pragma unroll
        for (int n = 0; n < 4; ++n) bfr[n] = *(const bf16x8*)(L + boff[n]);
#pragma unroll
        for (int m = 0; m < 4; ++m)
#pragma unroll
            for (int n = 0; n < 4; ++n)
                acc[m][n] = __builtin_amdgcn_mfma_f32_16x16x32_bf16(af[m], bfr[n], acc[m][n], 0, 0, 0);
        __syncthreads();
    }

#pragma unroll
    for (int m = 0; m < 4; ++m) {
#pragma unroll
        for (int rr = 0; rr < 4; ++rr) {
            int grow = row0 + wr * 64 + m * 16 + lg * 4 + rr;
            if (grow >= M) continue;
#pragma unroll
            for (int n = 0; n < 4; ++n) {
                int gcol = wc * 64 + n * 16 + l15;
                float v = fmaxf(acc[m][n][rr] + bias[gcol], 0.f);
                C[(long long)grow * 256 + gcol] = f2bf(v);
            }
        }
    }
}

// ====== GEMM 23: [p2 | self2+b2] = h1 @ wcat^T  (single K=256 pass, split epilogue) ======
__global__ __launch_bounds__(512)
void gemm23_kernel(const unsigned short* __restrict__ A, const unsigned short* __restrict__ WT,
                   const float* __restrict__ b2,
                   unsigned short* __restrict__ p2, unsigned short* __restrict__ self2, int M)
{
    const int K = 256;
    __shared__ __align__(16) char lds[2][24576];   // A: [0,8192)  B: [8192,24576)

    const int tid = threadIdx.x;
    const int wid = tid >> 6, lane = tid & 63;
    const int l15 = lane & 15, lg = lane >> 4;
    const int wr = wid >> 2, wc = wid & 3;
    const int row0 = blockIdx.x * 128;

    long long asrc; int adst;
    {
        int c = tid, r = c >> 2, s = c & 3;
        int kc = s ^ ((r >> 1) & 3);
        asrc = (long long)min(row0 + r, M - 1) * K + kc * 8;
        adst = c * 16;
    }
    long long bsrc[2]; int bdst[2];
#pragma unroll
    for (int i = 0; i < 2; ++i) {
        int c = wid * 128 + i * 64 + lane, r = c >> 2, s = c & 3;
        int kc = s ^ ((r >> 1) & 3);
        bsrc[i] = (long long)r * K + kc * 8;
        bdst[i] = 8192 + c * 16;
    }

    const int slot = (lg ^ ((l15 >> 1) & 3)) * 16;
    int aoff[4], boff[4];
#pragma unroll
    for (int m = 0; m < 4; ++m) aoff[m] = (wr * 64 + m * 16 + l15) * 64 + slot;
#pragma unroll
    for (int n = 0; n < 4; ++n) boff[n] = 8192 + (wc * 64 + n * 16 + l15) * 64 + slot;

    f32x4 acc[4][4] = {};

    auto stage = [&](int buf, int t) {
        int k0 = t * 32;
        gload16(A  + asrc + k0, &lds[buf][adst]);
        gload16(WT + bsrc[0] + k0, &lds[buf][bdst[0]]);
        gload16(WT + bsrc[1] + k0, &lds[buf][bdst[1]]);
    };

    stage(0, 0);
    __syncthreads();

    for (int t = 0; t < 8; ++t) {
        const int cur = t & 1;
        if (t + 1 < 8) stage(cur ^ 1, t + 1);
        const char* L = lds[cur];
        bf16x8 af[4], bfr[4];
#pragma unroll
        for (int m = 0; m < 4; ++m) af[m]  = *(const bf16x8*)(L + aoff[m]);
#pragma unroll
        for (int n = 0; n < 4; ++n) bfr[n] = *(const bf16x8*)(L + boff[n]);
#pragma unroll
        for (int m = 0; m < 4; ++m)
#pragma unroll
            for (int n = 0; n < 4; ++n)
                acc[m][n] = __builtin_amdgcn_mfma_f32_16x16x32_bf16(af[m], bfr[n], acc[m][n], 0, 0, 0);
        __syncthreads();
    }

    // epilogue: cols 0-127 (wc 0/1) -> p2; cols 128-255 (wc 2/3) -> self2 (+b2)
    if (wc < 2) {
#pragma unroll
        for (int m = 0; m < 4; ++m)
#pragma unroll
            for (int rr = 0; rr < 4; ++rr) {
                int grow = row0 + wr * 64 + m * 16 + lg * 4 + rr;
                if (grow >= M) continue;
#pragma unroll
                for (int n = 0; n < 4; ++n) {
                    int col = wc * 64 + n * 16 + l15;
                    p2[(long long)grow * 128 + col] = f2bf(acc[m][n][rr]);
                }
            }
    } else {
        float bv[4];
#pragma unroll
        for (int n = 0; n < 4; ++n) bv[n] = b2[(wc - 2) * 64 + n * 16 + l15];
#pragma unroll
        for (int m = 0; m < 4; ++m)
#pragma unroll
            for (int rr = 0; rr < 4; ++rr) {
                int grow = row0 + wr * 64 + m * 16 + lg * 4 + rr;
                if (grow >= M) continue;
#pragma unroll
                for (int n = 0; n < 4; ++n) {
                    int col = (wc - 2) * 64 + n * 16 + l15;
                    self2[(long long)grow * 128 + col] = f2bf(acc[m][n][rr] + bv[n]);
                }
            }
    }
}

// ===== gather128 + final: out = normalize(relu(self2 + mean_nb(p2))) , one wave/node =====
__global__ void gather_final_kernel(const unsigned short* __restrict__ p2, const int* __restrict__ off,
                                    const int* __restrict__ csr, const unsigned short* __restrict__ self2,
                                    float* __restrict__ out, int N) {
    int wid  = (int)((blockIdx.x * (long long)blockDim.x + threadIdx.x) >> 6);
    int lane = threadIdx.x & 63;
    if (wid >= N) return;
    int start = off[wid], end = off[wid + 1];
    const int g  = lane >> 4;            // 0..3: which row of the quad
    const int c8 = (lane & 15) * 8;      // 8 cols per lane -> 128
    float a[8] = {};
    int e = start;
    for (; e + 7 < end; e += 8) {        // 2 quads in flight
        int s0 = csr[e + g], s1 = csr[e + 4 + g];
        ushort8v v0 = *(const ushort8v*)(p2 + (long long)s0 * 128 + c8);
        ushort8v v1 = *(const ushort8v*)(p2 + (long long)s1 * 128 + c8);
#pragma unroll
        for (int j = 0; j < 8; ++j) a[j] += bf2f(v0[j]) + bf2f(v1[j]);
    }
    for (; e < end; e += 4) {
        int idx = e + g;
        if (idx < end) {
            int s = csr[idx];
            ushort8v v = *(const ushort8v*)(p2 + (long long)s * 128 + c8);
#pragma unroll
            for (int j = 0; j < 8; ++j) a[j] += bf2f(v[j]);
        }
    }
#pragma unroll
    for (int j = 0; j < 8; ++j) {
        a[j] += __shfl_xor(a[j], 16);
        a[j] += __shfl_xor(a[j], 32);
    }
    float invd = 1.0f / (float)max(end - start, 1);
    ushort8v sv = *(const ushort8v*)(self2 + (long long)wid * 128 + c8);
    float v[8];
    float ss = 0.f;
#pragma unroll
    for (int j = 0; j < 8; ++j) {
        v[j] = fmaxf(bf2f(sv[j]) + a[j] * invd, 0.f);
        ss += v[j] * v[j];
    }
    ss += __shfl_xor(ss, 1);
    ss += __shfl_xor(ss, 2);
    ss += __shfl_xor(ss, 4);
    ss += __shfl_xor(ss, 8);
    float inv = 1.0f / fmaxf(sqrtf(ss), 1e-12f);
    if (g == 0) {
        f32x4 o0 = { v[0] * inv, v[1] * inv, v[2] * inv, v[3] * inv };
        f32x4 o1 = { v[4] * inv, v[5] * inv, v[6] * inv, v[7] * inv };
        float* dstp = out + (long long)wid * 128 + c8;
        __builtin_nontemporal_store(o0, (f32x4*)dstp);     // final output: never re-read
        __builtin_nontemporal_store(o1, (f32x4*)(dstp + 4));
    }
}

extern "C" void kernel_launch(void* const* d_in, const int* in_sizes, int n_in,
                              void* d_out, int out_size, void* d_ws, size_t ws_size,
                              hipStream_t stream) {
    const float* feat     = (const float*)d_in[0];
    const int*   src      = (const int*)  d_in[1];
    const int*   dst      = (const int*)  d_in[2];
    const float* w_self1  = (const float*)d_in[3];
    const float* w_neigh1 = (const float*)d_in[4];
    const float* b1       = (const float*)d_in[5];
    const float* w_self2  = (const float*)d_in[6];
    const float* w_neigh2 = (const float*)d_in[7];
    const float* b2       = (const float*)d_in[8];
    float* out = (float*)d_out;

    const int N = in_sizes[0] / DIN;    // 100000
    const int E = in_sizes[1];          // 800000

    char* ws = (char*)d_ws;
    auto a4k = [](size_t x) { return (x + 4095) & ~(size_t)4095; };
    size_t o = 0;
    int* cnt  = (int*)(ws + o); o += a4k((size_t)N * 4);
    int* off  = (int*)(ws + o); o += a4k((size_t)(N + 1) * 4);
    int* part = (int*)(ws + o); o += a4k(1024);
    int* csr  = (int*)(ws + o); o += a4k((size_t)E * 4);
    unsigned short* ws1t = (unsigned short*)(ws + o); o += a4k((size_t)DIN * DH * 2);
    unsigned short* wn1t = (unsigned short*)(ws + o); o += a4k((size_t)DIN * DH * 2);
    unsigned short* wcat = (unsigned short*)(ws + o); o += a4k((size_t)256 * 256 * 2);
    unsigned int*   feat8 = (unsigned int*)(ws + o); o += a4k((size_t)N * DIN);       // fp8 mirror
    unsigned short* featb = (unsigned short*)(ws + o); o += a4k((size_t)N * DIN * 2);  // reused: p2b
    unsigned short* aggb  = (unsigned short*)(ws + o); o += a4k((size_t)N * DIN * 2);  // reused: self2b
    unsigned short* h1b   = (unsigned short*)(ws + o); o += a4k((size_t)N * DH * 2);

    unsigned short* p2b    = featb;   // dead after gemm1
    unsigned short* self2b = aggb;    // dead after gemm1

    const int nblk = (N + 1023) / 1024;   // 98

    // ---- prep: count (first) + wtrans + cvt (cnt zeroed first) ----
    hipMemsetAsync(cnt, 0, (size_t)N * 4, stream);
    long long ncHalf = (long long)N * DIN / 8;      // 3.2e6 f32x4 chunks per half
    const int bCnt = (E + 255) / 256;               // 3125
    const int bWt  = 768;
    const int bCvt = (int)((ncHalf + 255) / 256);   // 12500
    prep_kernel<<<bCnt + bWt + bCvt, 256, 0, stream>>>(
        feat, featb, feat8, ncHalf, w_self1, w_neigh1, w_self2, w_neigh2,
        ws1t, wn1t, wcat, dst, cnt, E, bCnt, bWt);

    // ---- CSR scan + fill (scan_partials fused into scan_block) ----
    block_sums_kernel<<<nblk, 256, 0, stream>>>(cnt, part, N);
    scan_block_kernel<<<nblk, 256, 0, stream>>>(cnt, part, off, N, E, nblk);
    fill_csr_kernel<<<(E + 255) / 256, 256, 0, stream>>>(src, dst, cnt, csr, E);

    const int mblk = (N + 127) / 128;   // 782

    // ---- layer 1: fp8 gather + bf16 MFMA GEMM ----
    gather_mean256_kernel<<<(N + 3) / 4, 256, 0, stream>>>(feat8, off, csr, aggb, N);
    gemm1_kernel<<<mblk, 512, 0, stream>>>(featb, ws1t, aggb, wn1t, b1, h1b, N);

    // ---- layer 2: both projections in one pass, then fused gather+norm ----
    gemm23_kernel<<<mblk, 512, 0, stream>>>(h1b, wcat, b2, p2b, self2b, N);
    gather_final_kernel<<<(N + 3) / 4, 256, 0, stream>>>(p2b, off, csr, self2b, out, N);
}